// Round 7
// baseline (1266.859 us; speedup 1.0000x reference)
//
#include <hip/hip_runtime.h>
#include <stdint.h>

typedef unsigned short u16;
typedef unsigned int u32;

#define B_ 2
#define T_ 2048
#define C_ 2048
#define H_ 32
#define M_ (B_*T_)              /* 4096 rows */
static const size_t MC = (size_t)M_ * C_;   /* 8388608 */

typedef __attribute__((ext_vector_type(8))) short s16x8;
typedef __attribute__((ext_vector_type(4))) float f32x4;

__device__ __forceinline__ u16 f2bf(float f) {
  union { float f; u32 u; } v; v.f = f;
  u32 r = v.u + 0x7FFFu + ((v.u >> 16) & 1u);
  return (u16)(r >> 16);
}
__device__ __forceinline__ float bits2f(u32 u) {
  union { u32 u; float f; } v; v.u = u; return v.f;
}
__device__ __forceinline__ u32 f2bits(float f) {
  union { float f; u32 u; } v; v.f = f; return v.u;
}
__device__ __forceinline__ float bf2f(u16 h) { return bits2f(((u32)h) << 16); }
__device__ __forceinline__ float sigm(float x) { return 1.0f / (1.0f + expf(-x)); }

__device__ __forceinline__ float wsum64(float x) {
  x += __shfl_xor(x, 32);
  x += __shfl_xor(x, 16);
  x += __shfl_xor(x, 8);
  x += __shfl_xor(x, 4);
  x += __shfl_xor(x, 2);
  x += __shfl_xor(x, 1);
  return x;
}

/* 4-group reduce over lanes {l, l^16, l^32, l^48} — VALU permlane path (no LDS pipe). */
#if __has_builtin(__builtin_amdgcn_permlane16_swap) && __has_builtin(__builtin_amdgcn_permlane32_swap)
typedef __attribute__((ext_vector_type(2))) unsigned int u32x2;
__device__ __forceinline__ float preduce4(float s) {
  u32 su = f2bits(s);
  u32x2 p1 = __builtin_amdgcn_permlane16_swap(su, su, false, false);
  float s1 = bits2f(p1.x) + bits2f(p1.y);
  u32 s1u = f2bits(s1);
  u32x2 p2 = __builtin_amdgcn_permlane32_swap(s1u, s1u, false, false);
  return bits2f(p2.x) + bits2f(p2.y);
}
#else
__device__ __forceinline__ float preduce4(float s) {
  return (s + __shfl_xor(s, 16)) + (__shfl_xor(s, 32) + __shfl_xor(s, 48));
}
#endif

#define GL2LDS(g, l) __builtin_amdgcn_global_load_lds( \
    (const __attribute__((address_space(1))) u32*)(g), \
    (__attribute__((address_space(3))) u32*)(l), 16, 0, 0)

/* ---------------- bf16 NT GEMM, 128x128 tile, BK=32 (m97 structure) ----------------
   C[M,N] = A[M,K] * B[N,K]^T ; A,B bf16 row-major (lda=ldb=K); C bf16 or fp32. */
template<bool BF16OUT>
__global__ void __launch_bounds__(256) gemm128(const u16* __restrict__ A, const u16* __restrict__ Bm,
                                               void* __restrict__ Cvp, int M, int N, int K) {
  __shared__ u16 As[128 * 32];
  __shared__ u16 Bs[128 * 32];
  const int tid = threadIdx.x;
  const int w = tid >> 6, l = tid & 63;
  const int wm = w >> 1, wn = w & 1;
  const int bm = blockIdx.x, bn = blockIdx.y;

  const int row0 = tid >> 2, kq0 = tid & 3;
  const u16* ag0 = A + (size_t)(bm * 128 + row0) * K + kq0 * 8;
  const u16* ag1 = ag0 + (size_t)64 * K;
  const u16* bg0 = Bm + (size_t)(bn * 128 + row0) * K + kq0 * 8;
  const u16* bg1 = bg0 + (size_t)64 * K;
  u16* al0 = &As[w * 512];
  u16* al1 = &As[2048 + w * 512];
  u16* bl0 = &Bs[w * 512];
  u16* bl1 = &Bs[2048 + w * 512];

  const int lrow = l & 15, lko = (l >> 4) * 8;
  const u16* Ars = &As[(wm * 64 + lrow) * 32 + lko];
  const u16* Brs = &Bs[(wn * 64 + lrow) * 32 + lko];

  f32x4 acc[4][4] = {};

  for (int k0 = 0; k0 < K; k0 += 32) {
    __syncthreads();
    GL2LDS(ag0, al0); GL2LDS(ag1, al1);
    GL2LDS(bg0, bl0); GL2LDS(bg1, bl1);
    ag0 += 32; ag1 += 32; bg0 += 32; bg1 += 32;
    __syncthreads();
    s16x8 af[4], bf[4];
#pragma unroll
    for (int m = 0; m < 4; ++m) af[m] = *(const s16x8*)(Ars + m * 16 * 32);
#pragma unroll
    for (int n = 0; n < 4; ++n) bf[n] = *(const s16x8*)(Brs + n * 16 * 32);
#pragma unroll
    for (int m = 0; m < 4; ++m)
#pragma unroll
      for (int n = 0; n < 4; ++n)
        acc[m][n] = __builtin_amdgcn_mfma_f32_16x16x32_bf16(af[m], bf[n], acc[m][n], 0, 0, 0);
  }

  const int crow0 = bm * 128 + wm * 64 + (l >> 4) * 4;
  const int ccol0 = bn * 128 + wn * 64 + (l & 15);
  if constexpr (BF16OUT) {
    u16* Cm = (u16*)Cvp;
#pragma unroll
    for (int m = 0; m < 4; ++m)
#pragma unroll
      for (int rr = 0; rr < 4; ++rr) {
        const int row = crow0 + m * 16 + rr;
        u16* cp = Cm + (size_t)row * N + ccol0;
#pragma unroll
        for (int n = 0; n < 4; ++n) cp[n * 16] = f2bf(acc[m][n][rr]);
      }
  } else {
    float* Cm = (float*)Cvp;
#pragma unroll
    for (int m = 0; m < 4; ++m)
#pragma unroll
      for (int rr = 0; rr < 4; ++rr) {
        const int row = crow0 + m * 16 + rr;
        float* cp = Cm + (size_t)row * N + ccol0;
#pragma unroll
        for (int n = 0; n < 4; ++n) cp[n * 16] = acc[m][n][rr];
      }
  }
}

/* ---------------- bf16 NT GEMM, 128x32 tile (small-N stage-1 LoRA GEMMs), fp32 out ---------------- */
__global__ void __launch_bounds__(256) gemm_bn32(const u16* __restrict__ A, const u16* __restrict__ Bm,
                                                 float* __restrict__ Cm, int M, int N, int K) {
  __shared__ u16 As[128 * 32];
  __shared__ u16 Bs[32 * 32];
  const int tid = threadIdx.x;
  const int w = tid >> 6, l = tid & 63;
  const int bm = blockIdx.x, bn = blockIdx.y;

  const int row0 = tid >> 2, kq0 = tid & 3;
  const u16* ag0 = A + (size_t)(bm * 128 + row0) * K + kq0 * 8;
  const u16* ag1 = ag0 + (size_t)64 * K;
  u16* al0 = &As[w * 512];
  u16* al1 = &As[2048 + w * 512];

  const int bc = (w & 1) * 64 + l;  /* chunk id for B staging (waves 0,1) */
  const u16* bg0 = Bm + (size_t)(bn * 32 + (bc >> 2)) * K + (bc & 3) * 8;
  u16* bl0 = &Bs[(w & 1) * 512];

  const int lrow = l & 15, lko = (l >> 4) * 8;
  const u16* Ars = &As[(w * 32 + lrow) * 32 + lko];
  const u16* Brs = &Bs[lrow * 32 + lko];

  f32x4 acc[2][2] = {};
  for (int k0 = 0; k0 < K; k0 += 32) {
    __syncthreads();
    GL2LDS(ag0, al0); GL2LDS(ag1, al1);
    if (w < 2) GL2LDS(bg0, bl0);
    ag0 += 32; ag1 += 32; bg0 += 32;
    __syncthreads();
    s16x8 af[2], bf[2];
    af[0] = *(const s16x8*)(Ars);
    af[1] = *(const s16x8*)(Ars + 16 * 32);
    bf[0] = *(const s16x8*)(Brs);
    bf[1] = *(const s16x8*)(Brs + 16 * 32);
#pragma unroll
    for (int m = 0; m < 2; ++m)
#pragma unroll
      for (int n = 0; n < 2; ++n)
        acc[m][n] = __builtin_amdgcn_mfma_f32_16x16x32_bf16(af[m], bf[n], acc[m][n], 0, 0, 0);
  }
  const int crow0 = bm * 128 + w * 32 + (l >> 4) * 4;
  const int ccol0 = bn * 32 + (l & 15);
#pragma unroll
  for (int m = 0; m < 2; ++m)
#pragma unroll
    for (int rr = 0; rr < 4; ++rr) {
      const int row = crow0 + m * 16 + rr;
      float* cp = Cm + (size_t)row * N + ccol0;
      cp[0] = acc[m][0][rr];
      cp[16] = acc[m][1][rr];
    }
}

/* ---------------- time-shift + 6 token mixes -> bf16 A matrices ---------------- */
__global__ void __launch_bounds__(256) prep_mix(const float* __restrict__ x,
    const float* __restrict__ mr, const float* __restrict__ mw, const float* __restrict__ mk,
    const float* __restrict__ mv, const float* __restrict__ ma, const float* __restrict__ mg,
    u16* __restrict__ xrb, u16* __restrict__ xwb, u16* __restrict__ xkb,
    u16* __restrict__ xvb, u16* __restrict__ xab, u16* __restrict__ xgb) {
  int gid = blockIdx.x * 256 + threadIdx.x;   /* 0 .. MC/8 */
  int row = gid >> 8;
  int col = (gid & 255) << 3;
  size_t base = (size_t)row * C_ + col;
  float xv[8], dx[8];
  *(float4*)&xv[0] = *(const float4*)(x + base);
  *(float4*)&xv[4] = *(const float4*)(x + base + 4);
  if ((row & (T_ - 1)) == 0) {
#pragma unroll
    for (int j = 0; j < 8; ++j) dx[j] = -xv[j];
  } else {
    float xp[8];
    *(float4*)&xp[0] = *(const float4*)(x + base - C_);
    *(float4*)&xp[4] = *(const float4*)(x + base - C_ + 4);
#pragma unroll
    for (int j = 0; j < 8; ++j) dx[j] = xp[j] - xv[j];
  }
#define EMIT(dst, mixp) { \
    float4 m0 = *(const float4*)(mixp + col); \
    float4 m1 = *(const float4*)(mixp + col + 4); \
    float o0 = xv[0] + dx[0] * m0.x, o1 = xv[1] + dx[1] * m0.y; \
    float o2 = xv[2] + dx[2] * m0.z, o3 = xv[3] + dx[3] * m0.w; \
    float o4 = xv[4] + dx[4] * m1.x, o5 = xv[5] + dx[5] * m1.y; \
    float o6 = xv[6] + dx[6] * m1.z, o7 = xv[7] + dx[7] * m1.w; \
    uint4 pk; \
    pk.x = (u32)f2bf(o0) | ((u32)f2bf(o1) << 16); \
    pk.y = (u32)f2bf(o2) | ((u32)f2bf(o3) << 16); \
    pk.z = (u32)f2bf(o4) | ((u32)f2bf(o5) << 16); \
    pk.w = (u32)f2bf(o6) | ((u32)f2bf(o7) << 16); \
    *(uint4*)(dst + base) = pk; }
  EMIT(xrb, mr) EMIT(xwb, mw) EMIT(xkb, mk) EMIT(xvb, mv) EMIT(xab, ma) EMIT(xgb, mg)
#undef EMIT
}

/* ---------------- fp32 -> bf16 (8 elems/thread) ---------------- */
__global__ void __launch_bounds__(256) convbf8(const float* __restrict__ in, u16* __restrict__ out, int n8) {
  int gid = blockIdx.x * 256 + threadIdx.x;
  if (gid >= n8) return;
  size_t b = (size_t)gid * 8;
  float4 a0 = *(const float4*)(in + b), a1 = *(const float4*)(in + b + 4);
  uint4 pk;
  pk.x = (u32)f2bf(a0.x) | ((u32)f2bf(a0.y) << 16);
  pk.y = (u32)f2bf(a0.z) | ((u32)f2bf(a0.w) << 16);
  pk.z = (u32)f2bf(a1.x) | ((u32)f2bf(a1.y) << 16);
  pk.w = (u32)f2bf(a1.z) | ((u32)f2bf(a1.w) << 16);
  *(uint4*)(out + b) = pk;
}

/* ---------------- transpose + bf16 convert: in[R][Cc] -> out[Cc][R] ---------------- */
__global__ void __launch_bounds__(256) tconvbf(const float* __restrict__ in, u16* __restrict__ out, int R, int Cc) {
  int gid = blockIdx.x * 256 + threadIdx.x;
  if (gid >= R * Cc) return;
  int i = gid % R, j = gid / R;
  out[gid] = f2bf(in[(size_t)i * Cc + j]);
}

/* ---------------- activation + bf16 convert (mode 0=tanh,1=id,2=sigmoid) ---------------- */
__global__ void __launch_bounds__(256) act_conv(const float* __restrict__ in, u16* __restrict__ out, int n, int mode) {
  int gid = blockIdx.x * 256 + threadIdx.x;
  if (gid >= n) return;
  float v = in[gid];
  if (mode == 0) v = tanhf(v);
  else if (mode == 2) v = sigm(v);
  out[gid] = f2bf(v);
}

/* ---------------- scan-prep: decay, kk-norm, k', v-blend, z, b, bonus ---------------- */
__global__ void __launch_bounds__(256) scan_prep(
    const u16* __restrict__ rb, u16* __restrict__ kb, u16* __restrict__ vb,
    const u16* __restrict__ dwb, u16* __restrict__ dab, u16* __restrict__ dvbb,
    const float* __restrict__ v_first,
    const float* __restrict__ a0, const float* __restrict__ v0, const float* __restrict__ w0,
    const float* __restrict__ k_k, const float* __restrict__ k_a, const float* __restrict__ r_k,
    float* __restrict__ dec, u16* __restrict__ bonus) {
  int rh = blockIdx.x * 4 + (threadIdx.x >> 6);
  int n = threadIdx.x & 63;
  int h = rh & (H_ - 1);
  size_t idx = (size_t)rh * 64 + n;
  int c = h * 64 + n;
  float kv = bf2f(kb[idx]), dav = bf2f(dab[idx]), dwv = bf2f(dwb[idx]);
  float dvv = bf2f(dvbb[idx]), vv = bf2f(vb[idx]);
  float vf = v_first[idx], rv = bf2f(rb[idx]);
  float av = sigm(a0[c] + dav);
  float kkv = kv * k_k[c];
  float ss = wsum64(kkv * kkv);
  float kkn = kkv / fmaxf(sqrtf(ss), 1e-12f);
  float k2 = kv * (1.f + (av - 1.f) * k_a[c]);
  float w_ = w0[c] + dwv;
  float wl = -log1pf(expf(-w_)) - 0.5f;
  float decf = expf(-expf(wl));
  float sv = sigm(v0[c] + dvv);
  float v2 = vv + (vf - vv) * sv;
  float bp = wsum64(rv * k2 * r_k[c]);
  kb[idx] = f2bf(k2);
  vb[idx] = f2bf(v2);
  dab[idx] = f2bf(kkn * av);   /* b */
  dvbb[idx] = f2bf(-kkn);      /* z */
  dec[idx] = decf;
  bonus[idx] = f2bf(bp * v2);
}

/* ---------------- RWKV7 sequential scan ----------------
   128 blocks x 128 threads = 2 INDEPENDENT waves per block (no barriers).
   Each wave: one 16-row unit of one (b,h). Lane = (row il, j-quarter q).
   Explicit per-step register double-buffer of next-step LDS slices. */
__device__ __forceinline__ void unpk8(u32 a, u32 b, u32 c, u32 d, float* o) {
  o[0] = bits2f(a << 16); o[1] = bits2f(a & 0xffff0000u);
  o[2] = bits2f(b << 16); o[3] = bits2f(b & 0xffff0000u);
  o[4] = bits2f(c << 16); o[5] = bits2f(c & 0xffff0000u);
  o[6] = bits2f(d << 16); o[7] = bits2f(d & 0xffff0000u);
}

__global__ void __launch_bounds__(128, 1) rwkv_scan(
    const u16* __restrict__ rb, const float* __restrict__ decb, const u16* __restrict__ kb,
    const u16* __restrict__ vb, const u16* __restrict__ zb, const u16* __restrict__ bbuf,
    float* __restrict__ yb) {
  __shared__ float Lr[2][16][68], Ld[2][16][68], Lk[2][16][68], Lz[2][16][68], Lb[2][16][68];
  __shared__ float Lv[2][16][20];
  const int tid = threadIdx.x;           /* 0..127 */
  const int wv = tid >> 6;               /* wave id 0/1 */
  const int ll = tid & 63;               /* lane */
  const int il = ll & 15;                /* local row */
  const int q = ll >> 4;                 /* j-quarter */
  const int unit = blockIdx.x * 2 + wv;  /* 0..255 */
  const int bh = unit >> 2;
  const int rblk = unit & 3;
  const int bbx = bh >> 5, h = bh & 31;
  const int i0 = rblk * 16;
  const size_t headbase = ((size_t)bbx * T_ * H_ + h) * 64;

  /* staging slot: lane loads 16 elems of one step for shared arrays, 4 v-elems */
  const int pt = ll >> 2;                /* step 0..15 */
  const int pc = (ll & 3) * 16;          /* col base */
  const size_t poff = headbase + (size_t)pt * C_ + pc;
  const size_t voff = headbase + (size_t)pt * C_ + i0 + (ll & 3) * 4;

  float S[16];
#pragma unroll
  for (int e = 0; e < 16; ++e) S[e] = 0.f;

  uint4 pr0, pr1, pk0, pk1, pz0, pz1, pb0, pb1;
  float4 pd0, pd1, pd2, pd3;
  uint2 pv;
  pr0 = *(const uint4*)(rb + poff);   pr1 = *(const uint4*)(rb + poff + 8);
  pk0 = *(const uint4*)(kb + poff);   pk1 = *(const uint4*)(kb + poff + 8);
  pz0 = *(const uint4*)(zb + poff);   pz1 = *(const uint4*)(zb + poff + 8);
  pb0 = *(const uint4*)(bbuf + poff); pb1 = *(const uint4*)(bbuf + poff + 8);
  pd0 = *(const float4*)(decb + poff);     pd1 = *(const float4*)(decb + poff + 4);
  pd2 = *(const float4*)(decb + poff + 8); pd3 = *(const float4*)(decb + poff + 12);
  pv  = *(const uint2*)(vb + voff);

  const int jb = q * 16;

  for (int ch = 0; ch < T_ / 16; ++ch) {
    /* ---- stage chunk into this wave's LDS region (same-wave in-order, no barrier) ---- */
    {
      float f[16];
      unpk8(pr0.x, pr0.y, pr0.z, pr0.w, f); unpk8(pr1.x, pr1.y, pr1.z, pr1.w, f + 8);
      *(float4*)&Lr[wv][pt][pc + 0] = *(float4*)&f[0];  *(float4*)&Lr[wv][pt][pc + 4] = *(float4*)&f[4];
      *(float4*)&Lr[wv][pt][pc + 8] = *(float4*)&f[8];  *(float4*)&Lr[wv][pt][pc + 12] = *(float4*)&f[12];
      unpk8(pk0.x, pk0.y, pk0.z, pk0.w, f); unpk8(pk1.x, pk1.y, pk1.z, pk1.w, f + 8);
      *(float4*)&Lk[wv][pt][pc + 0] = *(float4*)&f[0];  *(float4*)&Lk[wv][pt][pc + 4] = *(float4*)&f[4];
      *(float4*)&Lk[wv][pt][pc + 8] = *(float4*)&f[8];  *(float4*)&Lk[wv][pt][pc + 12] = *(float4*)&f[12];
      unpk8(pz0.x, pz0.y, pz0.z, pz0.w, f); unpk8(pz1.x, pz1.y, pz1.z, pz1.w, f + 8);
      *(float4*)&Lz[wv][pt][pc + 0] = *(float4*)&f[0];  *(float4*)&Lz[wv][pt][pc + 4] = *(float4*)&f[4];
      *(float4*)&Lz[wv][pt][pc + 8] = *(float4*)&f[8];  *(float4*)&Lz[wv][pt][pc + 12] = *(float4*)&f[12];
      unpk8(pb0.x, pb0.y, pb0.z, pb0.w, f); unpk8(pb1.x, pb1.y, pb1.z, pb1.w, f + 8);
      *(float4*)&Lb[wv][pt][pc + 0] = *(float4*)&f[0];  *(float4*)&Lb[wv][pt][pc + 4] = *(float4*)&f[4];
      *(float4*)&Lb[wv][pt][pc + 8] = *(float4*)&f[8];  *(float4*)&Lb[wv][pt][pc + 12] = *(float4*)&f[12];
      *(float4*)&Ld[wv][pt][pc + 0] = pd0;  *(float4*)&Ld[wv][pt][pc + 4] = pd1;
      *(float4*)&Ld[wv][pt][pc + 8] = pd2;  *(float4*)&Ld[wv][pt][pc + 12] = pd3;
      float g[4];
      g[0] = bits2f(pv.x << 16); g[1] = bits2f(pv.x & 0xffff0000u);
      g[2] = bits2f(pv.y << 16); g[3] = bits2f(pv.y & 0xffff0000u);
      *(float4*)&Lv[wv][pt][(ll & 3) * 4] = *(float4*)&g[0];
    }
    /* ---- HBM prefetch next chunk ---- */
    if (ch + 1 < T_ / 16) {
      size_t o2 = poff + (size_t)(ch + 1) * 16 * C_;
      size_t v2 = voff + (size_t)(ch + 1) * 16 * C_;
      pr0 = *(const uint4*)(rb + o2);   pr1 = *(const uint4*)(rb + o2 + 8);
      pk0 = *(const uint4*)(kb + o2);   pk1 = *(const uint4*)(kb + o2 + 8);
      pz0 = *(const uint4*)(zb + o2);   pz1 = *(const uint4*)(zb + o2 + 8);
      pb0 = *(const uint4*)(bbuf + o2); pb1 = *(const uint4*)(bbuf + o2 + 8);
      pd0 = *(const float4*)(decb + o2);     pd1 = *(const float4*)(decb + o2 + 4);
      pd2 = *(const float4*)(decb + o2 + 8); pd3 = *(const float4*)(decb + o2 + 12);
      pv  = *(const uint2*)(vb + v2);
    }

#define LOADSLICE(t, Z, D, Bv, K, R, VI) \
    *(float4*)&Z[0]  = *(const float4*)&Lz[wv][t][jb + 0]; \
    *(float4*)&Z[4]  = *(const float4*)&Lz[wv][t][jb + 4]; \
    *(float4*)&Z[8]  = *(const float4*)&Lz[wv][t][jb + 8]; \
    *(float4*)&Z[12] = *(const float4*)&Lz[wv][t][jb + 12]; \
    *(float4*)&D[0]  = *(const float4*)&Ld[wv][t][jb + 0]; \
    *(float4*)&D[4]  = *(const float4*)&Ld[wv][t][jb + 4]; \
    *(float4*)&D[8]  = *(const float4*)&Ld[wv][t][jb + 8]; \
    *(float4*)&D[12] = *(const float4*)&Ld[wv][t][jb + 12]; \
    *(float4*)&Bv[0]  = *(const float4*)&Lb[wv][t][jb + 0]; \
    *(float4*)&Bv[4]  = *(const float4*)&Lb[wv][t][jb + 4]; \
    *(float4*)&Bv[8]  = *(const float4*)&Lb[wv][t][jb + 8]; \
    *(float4*)&Bv[12] = *(const float4*)&Lb[wv][t][jb + 12]; \
    *(float4*)&K[0]  = *(const float4*)&Lk[wv][t][jb + 0]; \
    *(float4*)&K[4]  = *(const float4*)&Lk[wv][t][jb + 4]; \
    *(float4*)&K[8]  = *(const float4*)&Lk[wv][t][jb + 8]; \
    *(float4*)&K[12] = *(const float4*)&Lk[wv][t][jb + 12]; \
    *(float4*)&R[0]  = *(const float4*)&Lr[wv][t][jb + 0]; \
    *(float4*)&R[4]  = *(const float4*)&Lr[wv][t][jb + 4]; \
    *(float4*)&R[8]  = *(const float4*)&Lr[wv][t][jb + 8]; \
    *(float4*)&R[12] = *(const float4*)&Lr[wv][t][jb + 12]; \
    VI = Lv[wv][t][il];

    float zc[16], dc[16], bc[16], kc[16], rc[16], vc;
    LOADSLICE(0, zc, dc, bc, kc, rc, vc)

#pragma unroll
    for (int t = 0; t < 16; ++t) {
      /* prefetch next step's slices into fresh registers (issues before compute) */
      float zn[16], dn[16], bn[16], kn[16], rn[16], vn = 0.f;
      if (t < 15) {
        LOADSLICE(t + 1, zn, dn, bn, kn, rn, vn)
      }
      /* --- sa partial: products, pairwise tree, permlane reduce --- */
      float m[16];
#pragma unroll
      for (int e = 0; e < 16; ++e) m[e] = S[e] * zc[e];
#pragma unroll
      for (int st = 1; st < 16; st <<= 1)
#pragma unroll
        for (int e = 0; e < 16; e += 2 * st) m[e] = m[e] + m[e + st];
      float sa = preduce4(m[0]);

      /* --- update + y --- */
      float yp[16];
#pragma unroll
      for (int e = 0; e < 16; ++e) {
        float sn = S[e] * dc[e] + sa * bc[e] + vc * kc[e];
        S[e] = sn;
        yp[e] = sn * rc[e];
      }
#pragma unroll
      for (int st = 1; st < 16; st <<= 1)
#pragma unroll
        for (int e = 0; e < 16; e += 2 * st) yp[e] = yp[e] + yp[e + st];
      float y = preduce4(yp[0]);
      if (q == 0) yb[headbase + (size_t)(ch * 16 + t) * C_ + i0 + il] = y;

      /* rotate buffers (SSA-renamed away under full unroll) */
      if (t < 15) {
#pragma unroll
        for (int e = 0; e < 16; ++e) {
          zc[e] = zn[e]; dc[e] = dn[e]; bc[e] = bn[e]; kc[e] = kn[e]; rc[e] = rn[e];
        }
        vc = vn;
      }
    }
#undef LOADSLICE
  }
}

/* ---------------- GroupNorm(64/head) + bonus + gate -> bf16 A for final GEMM ---------------- */
__global__ void __launch_bounds__(256) gn_gg(
    const float* __restrict__ yb, const u16* __restrict__ bonus, const u16* __restrict__ gb,
    const float* __restrict__ gnw, const float* __restrict__ gnb,
    u16* __restrict__ ggb) {
  int rh = blockIdx.x * 4 + (threadIdx.x >> 6);
  int n = threadIdx.x & 63;
  int h = rh & (H_ - 1);
  size_t idx = (size_t)rh * 64 + n;
  int c = h * 64 + n;
  float y = yb[idx];
  float mu = wsum64(y) * (1.f / 64.f);
  float d = y - mu;
  float var = wsum64(d * d) * (1.f / 64.f);
  float yn = d * rsqrtf(var + 6.4e-4f) * gnw[c] + gnb[c];
  ggb[idx] = f2bf((yn + bf2f(bonus[idx])) * bf2f(gb[idx]));
}

extern "C" void kernel_launch(void* const* d_in, const int* in_sizes, int n_in,
                              void* d_out, int out_size, void* d_ws, size_t ws_size,
                              hipStream_t stream) {
  const float* x      = (const float*)d_in[0];
  const float* vfirst = (const float*)d_in[1];
  const float* x_r = (const float*)d_in[2];
  const float* x_w = (const float*)d_in[3];
  const float* x_k = (const float*)d_in[4];
  const float* x_v = (const float*)d_in[5];
  const float* x_a = (const float*)d_in[6];
  const float* x_g = (const float*)d_in[7];
  const float* w0  = (const float*)d_in[8];
  const float* w1  = (const float*)d_in[9];
  const float* w2  = (const float*)d_in[10];
  const float* a0  = (const float*)d_in[11];
  const float* a1  = (const float*)d_in[12];
  const float* a2  = (const float*)d_in[13];
  const float* v0  = (const float*)d_in[14];
  const float* v1  = (const float*)d_in[15];
  const float* v2  = (const float*)d_in[16];
  const float* g1  = (const float*)d_in[17];
  const float* g2  = (const float*)d_in[18];
  const float* k_k = (const float*)d_in[19];
  const float* k_a = (const float*)d_in[20];
  const float* r_k = (const float*)d_in[21];
  const float* W_r = (const float*)d_in[22];
  const float* W_k = (const float*)d_in[23];
  const float* W_v = (const float*)d_in[24];
  const float* W_o = (const float*)d_in[25];
  const float* gnw = (const float*)d_in[26];
  const float* gnb = (const float*)d_in[27];
  float* out = (float*)d_out;

  char* ws = (char*)d_ws;
  size_t off = 0;
  auto alloc = [&](size_t bytes) -> void* {
    void* p = ws + off;
    off += (bytes + 255) & ~(size_t)255;
    return p;
  };
  const size_t MCb2 = MC * 2;

  /* A-region: 6 contiguous 16MiB bf16 mix buffers, later reused */
  u16* xrb = (u16*)alloc(MCb2);   /* A0: xr -> dw_bf -> ggb            */
  u16* xwb = (u16*)alloc(MCb2);   /* A1: xw -> da_bf -> b_bf           */
  u16* xkb = (u16*)alloc(MCb2);   /* A2: xk -> dv_bf -> z_bf           */
  u16* xvb = (u16*)alloc(MCb2);   /* A3: xv -> g_bf                    */
  u16* xab = (u16*)alloc(MCb2);   /* A4: xa ┐                          */
  u16* xgb = (u16*)alloc(MCb2);   /* A5: xg ┘ -> yb fp32 (32MiB)       */
  u16* Wrb = (u16*)alloc((size_t)C_ * C_ * 2);
  u16* Wkb = (u16*)alloc((size_t)C_ * C_ * 2);
  u16* Wvb = (u16*)alloc((size_t)C_ * C_ * 2);
  u16* Wob = (u16*)alloc((size_t)C_ * C_ * 2);
  u16* w1t = (u16*)alloc((size_t)64 * C_ * 2);
  u16* a1t = (u16*)alloc((size_t)64 * C_ * 2);
  u16* v1t = (u16*)alloc((size_t)32 * C_ * 2);
  u16* g1t = (u16*)alloc((size_t)128 * C_ * 2);
  u16* w2t = (u16*)alloc((size_t)C_ * 64 * 2);
  u16* a2t = (u16*)alloc((size_t)C_ * 64 * 2);
  u16* v2t = (u16*)alloc((size_t)C_ * 32 * 2);
  u16* g2t = (u16*)alloc((size_t)C_ * 128 * 2);
  float* hw = (float*)alloc((size_t)M_ * 64 * 4);
  float* ha = (float*)alloc((size_t)M_ * 64 * 4);
  float* hv = (float*)alloc((size_t)M_ * 32 * 4);
  float* hg = (float*)alloc((size_t)M_ * 128 * 4);
  u16* hwb = (u16*)alloc((size_t)M_ * 64 * 2);
  u16* hab = (u16*)alloc((size_t)M_ * 64 * 2);
  u16* hvb = (u16*)alloc((size_t)M_ * 32 * 2);
  u16* hgb = (u16*)alloc((size_t)M_ * 128 * 2);
  u16* r_bf = (u16*)alloc(MCb2);            /* D0 */
  u16* k_bf = (u16*)alloc(MCb2);            /* D1: k -> k2 in place */
  u16* v_bf = (u16*)alloc(MCb2);            /* D2: v -> v2 in place */
  float* dec = (float*)alloc(MC * 4);       /* E0 fp32 */
  u16* bonus  = (u16*)alloc(MCb2);          /* E1 */
  /* aliases (regions dead at write time; see schedule) */
  u16* dw_bf = xrb;
  u16* da_bf = xwb;   /* then b_bf in place */
  u16* dv_bf = xkb;   /* then z_bf in place */
  u16* g_bf  = xvb;
  float* yb  = (float*)xab;  /* spans xab+xgb = 32 MiB */
  u16* ggb   = xrb;          /* after dw_bf consumed   */
  (void)ws_size; (void)in_sizes; (void)n_in; (void)out_size;

  dim3 blk(256);

  /* weight conversion */
  convbf8<<<(C_ * C_ / 8 + 255) / 256, blk, 0, stream>>>(W_r, Wrb, C_ * C_ / 8);
  convbf8<<<(C_ * C_ / 8 + 255) / 256, blk, 0, stream>>>(W_k, Wkb, C_ * C_ / 8);
  convbf8<<<(C_ * C_ / 8 + 255) / 256, blk, 0, stream>>>(W_v, Wvb, C_ * C_ / 8);
  convbf8<<<(C_ * C_ / 8 + 255) / 256, blk, 0, stream>>>(W_o, Wob, C_ * C_ / 8);
  tconvbf<<<(C_ * 64 + 255) / 256, blk, 0, stream>>>(w1, w1t, C_, 64);
  tconvbf<<<(C_ * 64 + 255) / 256, blk, 0, stream>>>(a1, a1t, C_, 64);
  tconvbf<<<(C_ * 32 + 255) / 256, blk, 0, stream>>>(v1, v1t, C_, 32);
  tconvbf<<<(C_ * 128 + 255) / 256, blk, 0, stream>>>(g1, g1t, C_, 128);
  tconvbf<<<(C_ * 64 + 255) / 256, blk, 0, stream>>>(w2, w2t, 64, C_);
  tconvbf<<<(C_ * 64 + 255) / 256, blk, 0, stream>>>(a2, a2t, 64, C_);
  tconvbf<<<(C_ * 32 + 255) / 256, blk, 0, stream>>>(v2, v2t, 32, C_);
  tconvbf<<<(C_ * 128 + 255) / 256, blk, 0, stream>>>(g2, g2t, 128, C_);

  /* time-shift mixes, v_first passthrough */
  prep_mix<<<(int)(MC / 8 / 256), blk, 0, stream>>>(x, x_r, x_w, x_k, x_v, x_a, x_g,
                                                    xrb, xwb, xkb, xvb, xab, xgb);
  hipMemcpyAsync(out + MC, vfirst, MC * sizeof(float), hipMemcpyDeviceToDevice, stream);

  /* big GEMMs: r, k, v (bf16 out) */
  dim3 g128(M_ / 128, C_ / 128);
  gemm128<true><<<g128, blk, 0, stream>>>(xrb, Wrb, r_bf, M_, C_, C_);
  gemm128<true><<<g128, blk, 0, stream>>>(xkb, Wkb, k_bf, M_, C_, C_);
  gemm128<true><<<g128, blk, 0, stream>>>(xvb, Wvb, v_bf, M_, C_, C_);

  /* LoRA stage-1 (fp32 out) */
  gemm_bn32<<<dim3(M_ / 128, 2), blk, 0, stream>>>(xwb, w1t, hw, M_, 64, C_);
  gemm_bn32<<<dim3(M_ / 128, 2), blk, 0, stream>>>(xab, a1t, ha, M_, 64, C_);
  gemm_bn32<<<dim3(M_ / 128, 1), blk, 0, stream>>>(xvb, v1t, hv, M_, 32, C_);
  gemm_bn32<<<dim3(M_ / 128, 4), blk, 0, stream>>>(xgb, g1t, hg, M_, 128, C_);

  /* activations + bf16 */
  act_conv<<<(M_ * 64 + 255) / 256, blk, 0, stream>>>(hw, hwb, M_ * 64, 0);
  act_conv<<<(M_ * 64 + 255) / 256, blk, 0, stream>>>(ha, hab, M_ * 64, 1);
  act_conv<<<(M_ * 32 + 255) / 256, blk, 0, stream>>>(hv, hvb, M_ * 32, 1);
  act_conv<<<(M_ * 128 + 255) / 256, blk, 0, stream>>>(hg, hgb, M_ * 128, 2);

  /* LoRA stage-2 (bf16 out, into dead mix regions) */
  gemm128<true><<<g128, blk, 0, stream>>>(hwb, w2t, dw_bf, M_, C_, 64);
  gemm128<true><<<g128, blk, 0, stream>>>(hab, a2t, da_bf, M_, C_, 64);
  gemm128<true><<<g128, blk, 0, stream>>>(hvb, v2t, dv_bf, M_, C_, 32);
  gemm128<true><<<g128, blk, 0, stream>>>(hgb, g2t, g_bf, M_, C_, 128);

  /* scan inputs (in-place bf16) + dec fp32 + bonus bf16 */
  scan_prep<<<M_ * H_ / 4, blk, 0, stream>>>(r_bf, k_bf, v_bf, dw_bf, da_bf, dv_bf, vfirst,
                                             a0, v0, w0, k_k, k_a, r_k, dec, bonus);

  /* sequential scan: 256 units on 128 blocks x 2 waves */
  rwkv_scan<<<dim3(128), dim3(128), 0, stream>>>(r_bf, dec, k_bf, v_bf, dv_bf, da_bf, yb);

  /* GroupNorm + bonus + gate -> bf16 */
  gn_gg<<<M_ * H_ / 4, blk, 0, stream>>>(yb, bonus, g_bf, gnw, gnb, ggb);

  /* output projection (fp32 out) */
  gemm128<false><<<g128, blk, 0, stream>>>(ggb, Wob, out, M_, C_, C_);
}

// Round 9
// 927.583 us; speedup vs baseline: 1.3658x; 1.3658x over previous
//
#include <hip/hip_runtime.h>
#include <stdint.h>

typedef unsigned short u16;
typedef unsigned int u32;

#define B_ 2
#define T_ 2048
#define C_ 2048
#define H_ 32
#define M_ (B_*T_)              /* 4096 rows */
static const size_t MC = (size_t)M_ * C_;   /* 8388608 */

typedef __attribute__((ext_vector_type(8))) short s16x8;
typedef __attribute__((ext_vector_type(4))) float f32x4;

__device__ __forceinline__ u16 f2bf(float f) {
  union { float f; u32 u; } v; v.f = f;
  u32 r = v.u + 0x7FFFu + ((v.u >> 16) & 1u);
  return (u16)(r >> 16);
}
__device__ __forceinline__ float bits2f(u32 u) {
  union { u32 u; float f; } v; v.u = u; return v.f;
}
__device__ __forceinline__ float bf2f(u16 h) { return bits2f(((u32)h) << 16); }
__device__ __forceinline__ float sigm(float x) { return 1.0f / (1.0f + expf(-x)); }

__device__ __forceinline__ float wsum64(float x) {
  x += __shfl_xor(x, 32);
  x += __shfl_xor(x, 16);
  x += __shfl_xor(x, 8);
  x += __shfl_xor(x, 4);
  x += __shfl_xor(x, 2);
  x += __shfl_xor(x, 1);
  return x;
}

#define GL2LDS(g, l) __builtin_amdgcn_global_load_lds( \
    (const __attribute__((address_space(1))) u32*)(g), \
    (__attribute__((address_space(3))) u32*)(l), 16, 0, 0)

/* ---------------- bf16 NT GEMM, 128x128 tile, BK=32 (m97 structure) ----------------
   C[M,N] = A[M,K] * B[N,K]^T ; A,B bf16 row-major (lda=ldb=K); C bf16 or fp32. */
template<bool BF16OUT>
__global__ void __launch_bounds__(256) gemm128(const u16* __restrict__ A, const u16* __restrict__ Bm,
                                               void* __restrict__ Cvp, int M, int N, int K) {
  __shared__ u16 As[128 * 32];
  __shared__ u16 Bs[128 * 32];
  const int tid = threadIdx.x;
  const int w = tid >> 6, l = tid & 63;
  const int wm = w >> 1, wn = w & 1;
  const int bm = blockIdx.x, bn = blockIdx.y;

  const int row0 = tid >> 2, kq0 = tid & 3;
  const u16* ag0 = A + (size_t)(bm * 128 + row0) * K + kq0 * 8;
  const u16* ag1 = ag0 + (size_t)64 * K;
  const u16* bg0 = Bm + (size_t)(bn * 128 + row0) * K + kq0 * 8;
  const u16* bg1 = bg0 + (size_t)64 * K;
  u16* al0 = &As[w * 512];
  u16* al1 = &As[2048 + w * 512];
  u16* bl0 = &Bs[w * 512];
  u16* bl1 = &Bs[2048 + w * 512];

  const int lrow = l & 15, lko = (l >> 4) * 8;
  const u16* Ars = &As[(wm * 64 + lrow) * 32 + lko];
  const u16* Brs = &Bs[(wn * 64 + lrow) * 32 + lko];

  f32x4 acc[4][4] = {};

  for (int k0 = 0; k0 < K; k0 += 32) {
    __syncthreads();
    GL2LDS(ag0, al0); GL2LDS(ag1, al1);
    GL2LDS(bg0, bl0); GL2LDS(bg1, bl1);
    ag0 += 32; ag1 += 32; bg0 += 32; bg1 += 32;
    __syncthreads();
    s16x8 af[4], bf[4];
#pragma unroll
    for (int m = 0; m < 4; ++m) af[m] = *(const s16x8*)(Ars + m * 16 * 32);
#pragma unroll
    for (int n = 0; n < 4; ++n) bf[n] = *(const s16x8*)(Brs + n * 16 * 32);
#pragma unroll
    for (int m = 0; m < 4; ++m)
#pragma unroll
      for (int n = 0; n < 4; ++n)
        acc[m][n] = __builtin_amdgcn_mfma_f32_16x16x32_bf16(af[m], bf[n], acc[m][n], 0, 0, 0);
  }

  const int crow0 = bm * 128 + wm * 64 + (l >> 4) * 4;
  const int ccol0 = bn * 128 + wn * 64 + (l & 15);
  if constexpr (BF16OUT) {
    u16* Cm = (u16*)Cvp;
#pragma unroll
    for (int m = 0; m < 4; ++m)
#pragma unroll
      for (int rr = 0; rr < 4; ++rr) {
        const int row = crow0 + m * 16 + rr;
        u16* cp = Cm + (size_t)row * N + ccol0;
#pragma unroll
        for (int n = 0; n < 4; ++n) cp[n * 16] = f2bf(acc[m][n][rr]);
      }
  } else {
    float* Cm = (float*)Cvp;
#pragma unroll
    for (int m = 0; m < 4; ++m)
#pragma unroll
      for (int rr = 0; rr < 4; ++rr) {
        const int row = crow0 + m * 16 + rr;
        float* cp = Cm + (size_t)row * N + ccol0;
#pragma unroll
        for (int n = 0; n < 4; ++n) cp[n * 16] = acc[m][n][rr];
      }
  }
}

/* ---------------- bf16 NT GEMM, 128x32 tile (small-N stage-1 LoRA GEMMs), fp32 out ---------------- */
__global__ void __launch_bounds__(256) gemm_bn32(const u16* __restrict__ A, const u16* __restrict__ Bm,
                                                 float* __restrict__ Cm, int M, int N, int K) {
  __shared__ u16 As[128 * 32];
  __shared__ u16 Bs[32 * 32];
  const int tid = threadIdx.x;
  const int w = tid >> 6, l = tid & 63;
  const int bm = blockIdx.x, bn = blockIdx.y;

  const int row0 = tid >> 2, kq0 = tid & 3;
  const u16* ag0 = A + (size_t)(bm * 128 + row0) * K + kq0 * 8;
  const u16* ag1 = ag0 + (size_t)64 * K;
  u16* al0 = &As[w * 512];
  u16* al1 = &As[2048 + w * 512];

  const int bc = (w & 1) * 64 + l;  /* chunk id for B staging (waves 0,1) */
  const u16* bg0 = Bm + (size_t)(bn * 32 + (bc >> 2)) * K + (bc & 3) * 8;
  u16* bl0 = &Bs[(w & 1) * 512];

  const int lrow = l & 15, lko = (l >> 4) * 8;
  const u16* Ars = &As[(w * 32 + lrow) * 32 + lko];
  const u16* Brs = &Bs[lrow * 32 + lko];

  f32x4 acc[2][2] = {};
  for (int k0 = 0; k0 < K; k0 += 32) {
    __syncthreads();
    GL2LDS(ag0, al0); GL2LDS(ag1, al1);
    if (w < 2) GL2LDS(bg0, bl0);
    ag0 += 32; ag1 += 32; bg0 += 32;
    __syncthreads();
    s16x8 af[2], bf[2];
    af[0] = *(const s16x8*)(Ars);
    af[1] = *(const s16x8*)(Ars + 16 * 32);
    bf[0] = *(const s16x8*)(Brs);
    bf[1] = *(const s16x8*)(Brs + 16 * 32);
#pragma unroll
    for (int m = 0; m < 2; ++m)
#pragma unroll
      for (int n = 0; n < 2; ++n)
        acc[m][n] = __builtin_amdgcn_mfma_f32_16x16x32_bf16(af[m], bf[n], acc[m][n], 0, 0, 0);
  }
  const int crow0 = bm * 128 + w * 32 + (l >> 4) * 4;
  const int ccol0 = bn * 32 + (l & 15);
#pragma unroll
  for (int m = 0; m < 2; ++m)
#pragma unroll
    for (int rr = 0; rr < 4; ++rr) {
      const int row = crow0 + m * 16 + rr;
      float* cp = Cm + (size_t)row * N + ccol0;
      cp[0] = acc[m][0][rr];
      cp[16] = acc[m][1][rr];
    }
}

/* ---------------- time-shift + 6 token mixes -> bf16 A matrices ---------------- */
__global__ void __launch_bounds__(256) prep_mix(const float* __restrict__ x,
    const float* __restrict__ mr, const float* __restrict__ mw, const float* __restrict__ mk,
    const float* __restrict__ mv, const float* __restrict__ ma, const float* __restrict__ mg,
    u16* __restrict__ xrb, u16* __restrict__ xwb, u16* __restrict__ xkb,
    u16* __restrict__ xvb, u16* __restrict__ xab, u16* __restrict__ xgb) {
  int gid = blockIdx.x * 256 + threadIdx.x;   /* 0 .. MC/8 */
  int row = gid >> 8;
  int col = (gid & 255) << 3;
  size_t base = (size_t)row * C_ + col;
  float xv[8], dx[8];
  *(float4*)&xv[0] = *(const float4*)(x + base);
  *(float4*)&xv[4] = *(const float4*)(x + base + 4);
  if ((row & (T_ - 1)) == 0) {
#pragma unroll
    for (int j = 0; j < 8; ++j) dx[j] = -xv[j];
  } else {
    float xp[8];
    *(float4*)&xp[0] = *(const float4*)(x + base - C_);
    *(float4*)&xp[4] = *(const float4*)(x + base - C_ + 4);
#pragma unroll
    for (int j = 0; j < 8; ++j) dx[j] = xp[j] - xv[j];
  }
#define EMIT(dst, mixp) { \
    float4 m0 = *(const float4*)(mixp + col); \
    float4 m1 = *(const float4*)(mixp + col + 4); \
    float o0 = xv[0] + dx[0] * m0.x, o1 = xv[1] + dx[1] * m0.y; \
    float o2 = xv[2] + dx[2] * m0.z, o3 = xv[3] + dx[3] * m0.w; \
    float o4 = xv[4] + dx[4] * m1.x, o5 = xv[5] + dx[5] * m1.y; \
    float o6 = xv[6] + dx[6] * m1.z, o7 = xv[7] + dx[7] * m1.w; \
    uint4 pk; \
    pk.x = (u32)f2bf(o0) | ((u32)f2bf(o1) << 16); \
    pk.y = (u32)f2bf(o2) | ((u32)f2bf(o3) << 16); \
    pk.z = (u32)f2bf(o4) | ((u32)f2bf(o5) << 16); \
    pk.w = (u32)f2bf(o6) | ((u32)f2bf(o7) << 16); \
    *(uint4*)(dst + base) = pk; }
  EMIT(xrb, mr) EMIT(xwb, mw) EMIT(xkb, mk) EMIT(xvb, mv) EMIT(xab, ma) EMIT(xgb, mg)
#undef EMIT
}

/* ---------------- fp32 -> bf16 (8 elems/thread) ---------------- */
__global__ void __launch_bounds__(256) convbf8(const float* __restrict__ in, u16* __restrict__ out, int n8) {
  int gid = blockIdx.x * 256 + threadIdx.x;
  if (gid >= n8) return;
  size_t b = (size_t)gid * 8;
  float4 a0 = *(const float4*)(in + b), a1 = *(const float4*)(in + b + 4);
  uint4 pk;
  pk.x = (u32)f2bf(a0.x) | ((u32)f2bf(a0.y) << 16);
  pk.y = (u32)f2bf(a0.z) | ((u32)f2bf(a0.w) << 16);
  pk.z = (u32)f2bf(a1.x) | ((u32)f2bf(a1.y) << 16);
  pk.w = (u32)f2bf(a1.z) | ((u32)f2bf(a1.w) << 16);
  *(uint4*)(out + b) = pk;
}

/* ---------------- transpose + bf16 convert: in[R][Cc] -> out[Cc][R] ---------------- */
__global__ void __launch_bounds__(256) tconvbf(const float* __restrict__ in, u16* __restrict__ out, int R, int Cc) {
  int gid = blockIdx.x * 256 + threadIdx.x;
  if (gid >= R * Cc) return;
  int i = gid % R, j = gid / R;
  out[gid] = f2bf(in[(size_t)i * Cc + j]);
}

/* ---------------- activation + bf16 convert (mode 0=tanh,1=id,2=sigmoid) ---------------- */
__global__ void __launch_bounds__(256) act_conv(const float* __restrict__ in, u16* __restrict__ out, int n, int mode) {
  int gid = blockIdx.x * 256 + threadIdx.x;
  if (gid >= n) return;
  float v = in[gid];
  if (mode == 0) v = tanhf(v);
  else if (mode == 2) v = sigm(v);
  out[gid] = f2bf(v);
}

/* ---------------- scan-prep: decay, kk-norm, k', v-blend, z, b, bonus ---------------- */
__global__ void __launch_bounds__(256) scan_prep(
    const u16* __restrict__ rb, u16* __restrict__ kb, u16* __restrict__ vb,
    const u16* __restrict__ dwb, u16* __restrict__ dab, u16* __restrict__ dvbb,
    const float* __restrict__ v_first,
    const float* __restrict__ a0, const float* __restrict__ v0, const float* __restrict__ w0,
    const float* __restrict__ k_k, const float* __restrict__ k_a, const float* __restrict__ r_k,
    float* __restrict__ dec, u16* __restrict__ bonus) {
  int rh = blockIdx.x * 4 + (threadIdx.x >> 6);
  int n = threadIdx.x & 63;
  int h = rh & (H_ - 1);
  size_t idx = (size_t)rh * 64 + n;
  int c = h * 64 + n;
  float kv = bf2f(kb[idx]), dav = bf2f(dab[idx]), dwv = bf2f(dwb[idx]);
  float dvv = bf2f(dvbb[idx]), vv = bf2f(vb[idx]);
  float vf = v_first[idx], rv = bf2f(rb[idx]);
  float av = sigm(a0[c] + dav);
  float kkv = kv * k_k[c];
  float ss = wsum64(kkv * kkv);
  float kkn = kkv / fmaxf(sqrtf(ss), 1e-12f);
  float k2 = kv * (1.f + (av - 1.f) * k_a[c]);
  float w_ = w0[c] + dwv;
  float wl = -log1pf(expf(-w_)) - 0.5f;
  float decf = expf(-expf(wl));
  float sv = sigm(v0[c] + dvv);
  float v2 = vv + (vf - vv) * sv;
  float bp = wsum64(rv * k2 * r_k[c]);
  kb[idx] = f2bf(k2);
  vb[idx] = f2bf(v2);
  dab[idx] = f2bf(kkn * av);   /* b */
  dvbb[idx] = f2bf(-kkn);      /* z */
  dec[idx] = decf;
  bonus[idx] = f2bf(bp * v2);
}

/* ---------------- RWKV7 chunked scan (WY form), chunk L=16, MFMA ----------------
   S_t = S_{t-1}(D_t + z_t b_t^T) + v_t k_t^T ;  y_t = S_t r_t.
   c_t = cumprod(d), c_0 = 1:
     z~ = z*c_{t-1}; b~ = b/c_t; k~ = k/c_t; r~ = r*c_t
     M_b = strictlow(Z~ B~^T); M_k = strictlow(Z~ K~^T)
     SA  = (I - M_b)^{-1} (Z~ S0^T + M_k V)
     Y   = R~ S0^T + tril(R~ B~^T) SA + tril(R~ K~^T) V
     S_L = (S0 + SA^T B~ + V^T K~) diag(c_L)
   All LDS tiles use power-of-two row strides (16B-aligned b128 fragment reads).
   Grid: 256 blocks = 64 heads x 4 value-row slices (16 rows each); 4 waves. */
__global__ void __launch_bounds__(256, 1) rwkv_scan(
    const u16* __restrict__ rb, const float* __restrict__ decb, const u16* __restrict__ kb,
    const u16* __restrict__ vb, const u16* __restrict__ zb, const u16* __restrict__ bbuf,
    float* __restrict__ yb) {
  __shared__ u16 Zt[16][64], Rt[16][64], Bt[16][64], Kt[16][64]; /* [t][j] scaled, bf16 */
  __shared__ u16 BKT[64][32];    /* [j][s]=b~[s][j], [j][16+s]=k~[s][j] */
  __shared__ u16 SAVT[16][32];   /* [i][s]=SA[s][i] (after sub), [i][16+s]=V[s][i0+i] */
  __shared__ u16 MK32[16][32];   /* [t][0..15]=0, [t][16+s]=M_k[t][s] strict-lower */
  __shared__ u16 MRBK[16][32];   /* [t][s]=M_rb tril, [t][16+s]=M_rk tril */
  __shared__ float Mb[16][17];   /* M_b strict-lower fp32 */
  __shared__ float basef[16][17];/* base[t][i] fp32 */
  __shared__ float Ldec[16][64];
  __shared__ float cum[17][68];  /* cum[0]=1, cum[t]=prod d_1..d_t */
  __shared__ float Sf[16][64];   /* state slice fp32 [i][j] */
  __shared__ u16 Sbf[16][64];    /* bf16 copy for MFMA B-operand */

  const int tid = threadIdx.x;
  const int w = tid >> 6, l = tid & 63;
  const int bh = blockIdx.x >> 2;
  const int rblk = blockIdx.x & 3;
  const int bbx = bh >> 5, h = bh & 31;
  const int i0 = rblk * 16;
  const size_t headbase = ((size_t)bbx * T_ * H_ + h) * 64;

  /* zero-init persistent LDS */
  for (int p = tid; p < 16 * 64; p += 256) { Sf[p >> 6][p & 63] = 0.f; Sbf[p >> 6][p & 63] = 0; }
  for (int p = tid; p < 16 * 32; p += 256) { SAVT[p >> 5][p & 31] = 0; MK32[p >> 5][p & 31] = 0; }
  __syncthreads();

  /* per-thread staging slot: 4 consecutive elems (t, j..j+3) */
  const int st_ = tid >> 4;
  const int sj = (tid & 15) * 4;
  const size_t g0 = headbase + (size_t)st_ * C_ + sj;

  uint2 cr, ck, cv, cz, cb; float4 cd;
  cr = *(const uint2*)(rb + g0);
  ck = *(const uint2*)(kb + g0);
  cv = *(const uint2*)(vb + g0);
  cz = *(const uint2*)(zb + g0);
  cb = *(const uint2*)(bbuf + g0);
  cd = *(const float4*)(decb + g0);

  const int lrow = l & 15, lko = (l >> 4) * 8;

  for (int ch = 0; ch < T_ / 16; ++ch) {
    /* P0: stage dec */
    *(float4*)&Ldec[st_][sj] = cd;
    __syncthreads();
    /* P1: cumulative decay (wave 0, lane = j) */
    if (w == 0) {
      float c = 1.f;
      cum[0][l] = 1.f;
#pragma unroll
      for (int t = 0; t < 16; ++t) { c *= Ldec[t][l]; cum[t + 1][l] = c; }
    }
    __syncthreads();
    /* P2: scale + write operand matrices; issue next-chunk HBM loads */
    {
      float4 cp = *(const float4*)&cum[st_][sj];
      float4 cc = *(const float4*)&cum[st_ + 1][sj];
      float rv[4], kv[4], zv[4], bv[4];
      rv[0] = bf2f((u16)(cr.x & 0xffff)); rv[1] = bf2f((u16)(cr.x >> 16));
      rv[2] = bf2f((u16)(cr.y & 0xffff)); rv[3] = bf2f((u16)(cr.y >> 16));
      kv[0] = bf2f((u16)(ck.x & 0xffff)); kv[1] = bf2f((u16)(ck.x >> 16));
      kv[2] = bf2f((u16)(ck.y & 0xffff)); kv[3] = bf2f((u16)(ck.y >> 16));
      zv[0] = bf2f((u16)(cz.x & 0xffff)); zv[1] = bf2f((u16)(cz.x >> 16));
      zv[2] = bf2f((u16)(cz.y & 0xffff)); zv[3] = bf2f((u16)(cz.y >> 16));
      bv[0] = bf2f((u16)(cb.x & 0xffff)); bv[1] = bf2f((u16)(cb.x >> 16));
      bv[2] = bf2f((u16)(cb.y & 0xffff)); bv[3] = bf2f((u16)(cb.y >> 16));
      float cpv[4] = {cp.x, cp.y, cp.z, cp.w};
      float ccv[4] = {cc.x, cc.y, cc.z, cc.w};
      u16 zt4[4], rt4[4], bt4[4], kt4[4];
#pragma unroll
      for (int m = 0; m < 4; ++m) {
        float inv = 1.0f / ccv[m];
        zt4[m] = f2bf(zv[m] * cpv[m]);
        rt4[m] = f2bf(rv[m] * ccv[m]);
        bt4[m] = f2bf(bv[m] * inv);
        kt4[m] = f2bf(kv[m] * inv);
      }
      *(uint2*)&Zt[st_][sj] = *(uint2*)zt4;
      *(uint2*)&Rt[st_][sj] = *(uint2*)rt4;
      *(uint2*)&Bt[st_][sj] = *(uint2*)bt4;
      *(uint2*)&Kt[st_][sj] = *(uint2*)kt4;
#pragma unroll
      for (int m = 0; m < 4; ++m) {
        BKT[sj + m][st_] = bt4[m];
        BKT[sj + m][16 + st_] = kt4[m];
      }
      if ((sj >> 4) == rblk) {
        u16 vv4[4];
        vv4[0] = (u16)(cv.x & 0xffff); vv4[1] = (u16)(cv.x >> 16);
        vv4[2] = (u16)(cv.y & 0xffff); vv4[3] = (u16)(cv.y >> 16);
#pragma unroll
        for (int m = 0; m < 4; ++m) SAVT[(sj & 15) + m][16 + st_] = vv4[m];
      }
      if (ch + 1 < T_ / 16) {
        size_t g2 = g0 + (size_t)(ch + 1) * 16 * C_;
        cr = *(const uint2*)(rb + g2);
        ck = *(const uint2*)(kb + g2);
        cv = *(const uint2*)(vb + g2);
        cz = *(const uint2*)(zb + g2);
        cb = *(const uint2*)(bbuf + g2);
        cd = *(const float4*)(decb + g2);
      }
    }
    __syncthreads();
    /* P3: MFMA set A (per-wave) + base/Y part-1.
       w0: M_b = Z~B~^T, keep = Z~S0^T ; w1: M_k = Z~K~^T, keep = R~S0^T ;
       w2: M_rb = R~B~^T ; w3: M_rk = R~K~^T */
    f32x4 keep = {};
    {
      s16x8 a0f, a1f, b0f, b1f;
      if (w == 0 || w == 1) {
        a0f = *(const s16x8*)&Zt[lrow][lko];
        a1f = *(const s16x8*)&Zt[lrow][32 + lko];
      } else {
        a0f = *(const s16x8*)&Rt[lrow][lko];
        a1f = *(const s16x8*)&Rt[lrow][32 + lko];
      }
      if (w == 0 || w == 2) {
        b0f = *(const s16x8*)&Bt[lrow][lko];
        b1f = *(const s16x8*)&Bt[lrow][32 + lko];
      } else {
        b0f = *(const s16x8*)&Kt[lrow][lko];
        b1f = *(const s16x8*)&Kt[lrow][32 + lko];
      }
      f32x4 macc = {};
      macc = __builtin_amdgcn_mfma_f32_16x16x32_bf16(a0f, b0f, macc, 0, 0, 0);
      macc = __builtin_amdgcn_mfma_f32_16x16x32_bf16(a1f, b1f, macc, 0, 0, 0);
      const int s = l & 15;
#pragma unroll
      for (int rr = 0; rr < 4; ++rr) {
        int t = (l >> 4) * 4 + rr;
        float v = macc[rr];
        if (w == 0) Mb[t][s] = (s < t) ? v : 0.f;
        else if (w == 1) MK32[t][16 + s] = f2bf((s < t) ? v : 0.f);
        else if (w == 2) MRBK[t][s] = f2bf((s <= t) ? v : 0.f);
        else MRBK[t][16 + s] = f2bf((s <= t) ? v : 0.f);
      }
      if (w == 0 || w == 1) {
        s16x8 s0f = *(const s16x8*)&Sbf[lrow][lko];
        s16x8 s1f = *(const s16x8*)&Sbf[lrow][32 + lko];
        if (w == 0) {
          keep = __builtin_amdgcn_mfma_f32_16x16x32_bf16(a0f, s0f, keep, 0, 0, 0);
          keep = __builtin_amdgcn_mfma_f32_16x16x32_bf16(a1f, s1f, keep, 0, 0, 0);
        } else {
          /* Y1 must use R~ fragments (bug fixed vs R8) */
          s16x8 ra0 = *(const s16x8*)&Rt[lrow][lko];
          s16x8 ra1 = *(const s16x8*)&Rt[lrow][32 + lko];
          keep = __builtin_amdgcn_mfma_f32_16x16x32_bf16(ra0, s0f, keep, 0, 0, 0);
          keep = __builtin_amdgcn_mfma_f32_16x16x32_bf16(ra1, s1f, keep, 0, 0, 0);
        }
      }
    }
    __syncthreads();
    /* P4+P5: wave0: base += [0|M_k] x SAVT ; forward substitution -> SA */
    if (w == 0) {
      s16x8 af = *(const s16x8*)&MK32[lrow][lko];
      s16x8 bf = *(const s16x8*)&SAVT[lrow][lko];
      keep = __builtin_amdgcn_mfma_f32_16x16x32_bf16(af, bf, keep, 0, 0, 0);
      const int i = l & 15;
#pragma unroll
      for (int rr = 0; rr < 4; ++rr) basef[(l >> 4) * 4 + rr][i] = keep[rr];
      float sa[16];
#pragma unroll
      for (int t = 0; t < 16; ++t) {
        float acc = basef[t][i];
#pragma unroll
        for (int s = 0; s < 16; ++s) {
          if (s < t) acc += Mb[t][s] * sa[s];
        }
        sa[t] = acc;
      }
      if (l < 16) {
        u32* dst = (u32*)&SAVT[l][0];
#pragma unroll
        for (int m = 0; m < 8; ++m)
          dst[m] = (u32)f2bf(sa[2 * m]) | ((u32)f2bf(sa[2 * m + 1]) << 16);
      }
    }
    __syncthreads();
    /* P6: Y finish + store (wave1); state update (all waves, one j-tile each) */
    if (w == 1) {
      s16x8 af = *(const s16x8*)&MRBK[lrow][lko];
      s16x8 bf = *(const s16x8*)&SAVT[lrow][lko];
      f32x4 yacc = __builtin_amdgcn_mfma_f32_16x16x32_bf16(af, bf, keep, 0, 0, 0);
#pragma unroll
      for (int rr = 0; rr < 4; ++rr) {
        int t = (l >> 4) * 4 + rr;
        yb[headbase + (size_t)(ch * 16 + t) * C_ + i0 + (l & 15)] = yacc[rr];
      }
    }
    {
      const int j0 = w * 16;
      s16x8 af = *(const s16x8*)&SAVT[lrow][lko];
      s16x8 bf = *(const s16x8*)&BKT[j0 + lrow][lko];
      f32x4 up = {};
      up = __builtin_amdgcn_mfma_f32_16x16x32_bf16(af, bf, up, 0, 0, 0);
      const int j = j0 + (l & 15);
      float cl = cum[16][j];
#pragma unroll
      for (int rr = 0; rr < 4; ++rr) {
        int i = (l >> 4) * 4 + rr;
        float sn = (Sf[i][j] + up[rr]) * cl;
        Sf[i][j] = sn;
        Sbf[i][j] = f2bf(sn);
      }
    }
    __syncthreads();
  }
}

/* ---------------- GroupNorm(64/head) + bonus + gate -> bf16 A for final GEMM ---------------- */
__global__ void __launch_bounds__(256) gn_gg(
    const float* __restrict__ yb, const u16* __restrict__ bonus, const u16* __restrict__ gb,
    const float* __restrict__ gnw, const float* __restrict__ gnb,
    u16* __restrict__ ggb) {
  int rh = blockIdx.x * 4 + (threadIdx.x >> 6);
  int n = threadIdx.x & 63;
  int h = rh & (H_ - 1);
  size_t idx = (size_t)rh * 64 + n;
  int c = h * 64 + n;
  float y = yb[idx];
  float mu = wsum64(y) * (1.f / 64.f);
  float d = y - mu;
  float var = wsum64(d * d) * (1.f / 64.f);
  float yn = d * rsqrtf(var + 6.4e-4f) * gnw[c] + gnb[c];
  ggb[idx] = f2bf((yn + bf2f(bonus[idx])) * bf2f(gb[idx]));
}

extern "C" void kernel_launch(void* const* d_in, const int* in_sizes, int n_in,
                              void* d_out, int out_size, void* d_ws, size_t ws_size,
                              hipStream_t stream) {
  const float* x      = (const float*)d_in[0];
  const float* vfirst = (const float*)d_in[1];
  const float* x_r = (const float*)d_in[2];
  const float* x_w = (const float*)d_in[3];
  const float* x_k = (const float*)d_in[4];
  const float* x_v = (const float*)d_in[5];
  const float* x_a = (const float*)d_in[6];
  const float* x_g = (const float*)d_in[7];
  const float* w0  = (const float*)d_in[8];
  const float* w1  = (const float*)d_in[9];
  const float* w2  = (const float*)d_in[10];
  const float* a0  = (const float*)d_in[11];
  const float* a1  = (const float*)d_in[12];
  const float* a2  = (const float*)d_in[13];
  const float* v0  = (const float*)d_in[14];
  const float* v1  = (const float*)d_in[15];
  const float* v2  = (const float*)d_in[16];
  const float* g1  = (const float*)d_in[17];
  const float* g2  = (const float*)d_in[18];
  const float* k_k = (const float*)d_in[19];
  const float* k_a = (const float*)d_in[20];
  const float* r_k = (const float*)d_in[21];
  const float* W_r = (const float*)d_in[22];
  const float* W_k = (const float*)d_in[23];
  const float* W_v = (const float*)d_in[24];
  const float* W_o = (const float*)d_in[25];
  const float* gnw = (const float*)d_in[26];
  const float* gnb = (const float*)d_in[27];
  float* out = (float*)d_out;

  char* ws = (char*)d_ws;
  size_t off = 0;
  auto alloc = [&](size_t bytes) -> void* {
    void* p = ws + off;
    off += (bytes + 255) & ~(size_t)255;
    return p;
  };
  const size_t MCb2 = MC * 2;

  /* A-region: 6 contiguous 16MiB bf16 mix buffers, later reused */
  u16* xrb = (u16*)alloc(MCb2);   /* A0: xr -> dw_bf -> ggb            */
  u16* xwb = (u16*)alloc(MCb2);   /* A1: xw -> da_bf -> b_bf           */
  u16* xkb = (u16*)alloc(MCb2);   /* A2: xk -> dv_bf -> z_bf           */
  u16* xvb = (u16*)alloc(MCb2);   /* A3: xv -> g_bf                    */
  u16* xab = (u16*)alloc(MCb2);   /* A4: xa ┐                          */
  u16* xgb = (u16*)alloc(MCb2);   /* A5: xg ┘ -> yb fp32 (32MiB)       */
  u16* Wrb = (u16*)alloc((size_t)C_ * C_ * 2);
  u16* Wkb = (u16*)alloc((size_t)C_ * C_ * 2);
  u16* Wvb = (u16*)alloc((size_t)C_ * C_ * 2);
  u16* Wob = (u16*)alloc((size_t)C_ * C_ * 2);
  u16* w1t = (u16*)alloc((size_t)64 * C_ * 2);
  u16* a1t = (u16*)alloc((size_t)64 * C_ * 2);
  u16* v1t = (u16*)alloc((size_t)32 * C_ * 2);
  u16* g1t = (u16*)alloc((size_t)128 * C_ * 2);
  u16* w2t = (u16*)alloc((size_t)C_ * 64 * 2);
  u16* a2t = (u16*)alloc((size_t)C_ * 64 * 2);
  u16* v2t = (u16*)alloc((size_t)C_ * 32 * 2);
  u16* g2t = (u16*)alloc((size_t)C_ * 128 * 2);
  float* hw = (float*)alloc((size_t)M_ * 64 * 4);
  float* ha = (float*)alloc((size_t)M_ * 64 * 4);
  float* hv = (float*)alloc((size_t)M_ * 32 * 4);
  float* hg = (float*)alloc((size_t)M_ * 128 * 4);
  u16* hwb = (u16*)alloc((size_t)M_ * 64 * 2);
  u16* hab = (u16*)alloc((size_t)M_ * 64 * 2);
  u16* hvb = (u16*)alloc((size_t)M_ * 32 * 2);
  u16* hgb = (u16*)alloc((size_t)M_ * 128 * 2);
  u16* r_bf = (u16*)alloc(MCb2);            /* D0 */
  u16* k_bf = (u16*)alloc(MCb2);            /* D1: k -> k2 in place */
  u16* v_bf = (u16*)alloc(MCb2);            /* D2: v -> v2 in place */
  float* dec = (float*)alloc(MC * 4);       /* E0 fp32 */
  u16* bonus  = (u16*)alloc(MCb2);          /* E1 */
  /* aliases (regions dead at write time; see schedule) */
  u16* dw_bf = xrb;
  u16* da_bf = xwb;   /* then b_bf in place */
  u16* dv_bf = xkb;   /* then z_bf in place */
  u16* g_bf  = xvb;
  float* yb  = (float*)xab;  /* spans xab+xgb = 32 MiB */
  u16* ggb   = xrb;          /* after dw_bf consumed   */
  (void)ws_size; (void)in_sizes; (void)n_in; (void)out_size;

  dim3 blk(256);

  /* weight conversion */
  convbf8<<<(C_ * C_ / 8 + 255) / 256, blk, 0, stream>>>(W_r, Wrb, C_ * C_ / 8);
  convbf8<<<(C_ * C_ / 8 + 255) / 256, blk, 0, stream>>>(W_k, Wkb, C_ * C_ / 8);
  convbf8<<<(C_ * C_ / 8 + 255) / 256, blk, 0, stream>>>(W_v, Wvb, C_ * C_ / 8);
  convbf8<<<(C_ * C_ / 8 + 255) / 256, blk, 0, stream>>>(W_o, Wob, C_ * C_ / 8);
  tconvbf<<<(C_ * 64 + 255) / 256, blk, 0, stream>>>(w1, w1t, C_, 64);
  tconvbf<<<(C_ * 64 + 255) / 256, blk, 0, stream>>>(a1, a1t, C_, 64);
  tconvbf<<<(C_ * 32 + 255) / 256, blk, 0, stream>>>(v1, v1t, C_, 32);
  tconvbf<<<(C_ * 128 + 255) / 256, blk, 0, stream>>>(g1, g1t, C_, 128);
  tconvbf<<<(C_ * 64 + 255) / 256, blk, 0, stream>>>(w2, w2t, 64, C_);
  tconvbf<<<(C_ * 64 + 255) / 256, blk, 0, stream>>>(a2, a2t, 64, C_);
  tconvbf<<<(C_ * 32 + 255) / 256, blk, 0, stream>>>(v2, v2t, 32, C_);
  tconvbf<<<(C_ * 128 + 255) / 256, blk, 0, stream>>>(g2, g2t, 128, C_);

  /* time-shift mixes, v_first passthrough */
  prep_mix<<<(int)(MC / 8 / 256), blk, 0, stream>>>(x, x_r, x_w, x_k, x_v, x_a, x_g,
                                                    xrb, xwb, xkb, xvb, xab, xgb);
  hipMemcpyAsync(out + MC, vfirst, MC * sizeof(float), hipMemcpyDeviceToDevice, stream);

  /* big GEMMs: r, k, v (bf16 out) */
  dim3 g128(M_ / 128, C_ / 128);
  gemm128<true><<<g128, blk, 0, stream>>>(xrb, Wrb, r_bf, M_, C_, C_);
  gemm128<true><<<g128, blk, 0, stream>>>(xkb, Wkb, k_bf, M_, C_, C_);
  gemm128<true><<<g128, blk, 0, stream>>>(xvb, Wvb, v_bf, M_, C_, C_);

  /* LoRA stage-1 (fp32 out) */
  gemm_bn32<<<dim3(M_ / 128, 2), blk, 0, stream>>>(xwb, w1t, hw, M_, 64, C_);
  gemm_bn32<<<dim3(M_ / 128, 2), blk, 0, stream>>>(xab, a1t, ha, M_, 64, C_);
  gemm_bn32<<<dim3(M_ / 128, 1), blk, 0, stream>>>(xvb, v1t, hv, M_, 32, C_);
  gemm_bn32<<<dim3(M_ / 128, 4), blk, 0, stream>>>(xgb, g1t, hg, M_, 128, C_);

  /* activations + bf16 */
  act_conv<<<(M_ * 64 + 255) / 256, blk, 0, stream>>>(hw, hwb, M_ * 64, 0);
  act_conv<<<(M_ * 64 + 255) / 256, blk, 0, stream>>>(ha, hab, M_ * 64, 1);
  act_conv<<<(M_ * 32 + 255) / 256, blk, 0, stream>>>(hv, hvb, M_ * 32, 1);
  act_conv<<<(M_ * 128 + 255) / 256, blk, 0, stream>>>(hg, hgb, M_ * 128, 2);

  /* LoRA stage-2 (bf16 out, into dead mix regions) */
  gemm128<true><<<g128, blk, 0, stream>>>(hwb, w2t, dw_bf, M_, C_, 64);
  gemm128<true><<<g128, blk, 0, stream>>>(hab, a2t, da_bf, M_, C_, 64);
  gemm128<true><<<g128, blk, 0, stream>>>(hvb, v2t, dv_bf, M_, C_, 32);
  gemm128<true><<<g128, blk, 0, stream>>>(hgb, g2t, g_bf, M_, C_, 128);

  /* scan inputs (in-place bf16) + dec fp32 + bonus bf16 */
  scan_prep<<<M_ * H_ / 4, blk, 0, stream>>>(r_bf, k_bf, v_bf, dw_bf, da_bf, dv_bf, vfirst,
                                             a0, v0, w0, k_k, k_a, r_k, dec, bonus);

  /* chunked scan: 256 blocks (64 heads x 4 row-slices) x 256 threads */
  rwkv_scan<<<dim3(256), dim3(256), 0, stream>>>(r_bf, dec, k_bf, v_bf, dv_bf, da_bf, yb);

  /* GroupNorm + bonus + gate -> bf16 */
  gn_gg<<<M_ * H_ / 4, blk, 0, stream>>>(yb, bonus, g_bf, gnw, gnb, ggb);

  /* output projection (fp32 out) */
  gemm128<false><<<g128, blk, 0, stream>>>(ggb, Wob, out, M_, C_, C_);
}

// Round 10
// 704.937 us; speedup vs baseline: 1.7971x; 1.3158x over previous
//
#include <hip/hip_runtime.h>
#include <stdint.h>

typedef unsigned short u16;
typedef unsigned int u32;

#define B_ 2
#define T_ 2048
#define C_ 2048
#define H_ 32
#define M_ (B_*T_)              /* 4096 rows */
static const size_t MC = (size_t)M_ * C_;   /* 8388608 */

typedef __attribute__((ext_vector_type(8))) short s16x8;
typedef __attribute__((ext_vector_type(4))) float f32x4;

__device__ __forceinline__ u16 f2bf(float f) {
  union { float f; u32 u; } v; v.f = f;
  u32 r = v.u + 0x7FFFu + ((v.u >> 16) & 1u);
  return (u16)(r >> 16);
}
__device__ __forceinline__ float bits2f(u32 u) {
  union { u32 u; float f; } v; v.u = u; return v.f;
}
__device__ __forceinline__ float bf2f(u16 h) { return bits2f(((u32)h) << 16); }
__device__ __forceinline__ float sigm(float x) { return 1.0f / (1.0f + expf(-x)); }

__device__ __forceinline__ float wsum64(float x) {
  x += __shfl_xor(x, 32);
  x += __shfl_xor(x, 16);
  x += __shfl_xor(x, 8);
  x += __shfl_xor(x, 4);
  x += __shfl_xor(x, 2);
  x += __shfl_xor(x, 1);
  return x;
}

#define GL2LDS(g, l) __builtin_amdgcn_global_load_lds( \
    (const __attribute__((address_space(1))) u32*)(g), \
    (__attribute__((address_space(3))) u32*)(l), 16, 0, 0)

/* ---------------- bf16 NT GEMM, 128x128 tile, BK=32; fp32 C (W_o) ---------------- */
__global__ void __launch_bounds__(256) gemm128f(const u16* __restrict__ A, const u16* __restrict__ Bm,
                                                float* __restrict__ Cm, int M, int N, int K) {
  __shared__ u16 As[128 * 32];
  __shared__ u16 Bs[128 * 32];
  const int tid = threadIdx.x;
  const int w = tid >> 6, l = tid & 63;
  const int wm = w >> 1, wn = w & 1;
  const int bm = blockIdx.x, bn = blockIdx.y;

  const int row0 = tid >> 2, kq0 = tid & 3;
  const u16* ag0 = A + (size_t)(bm * 128 + row0) * K + kq0 * 8;
  const u16* ag1 = ag0 + (size_t)64 * K;
  const u16* bg0 = Bm + (size_t)(bn * 128 + row0) * K + kq0 * 8;
  const u16* bg1 = bg0 + (size_t)64 * K;
  u16* al0 = &As[w * 512];
  u16* al1 = &As[2048 + w * 512];
  u16* bl0 = &Bs[w * 512];
  u16* bl1 = &Bs[2048 + w * 512];

  const int lrow = l & 15, lko = (l >> 4) * 8;
  const u16* Ars = &As[(wm * 64 + lrow) * 32 + lko];
  const u16* Brs = &Bs[(wn * 64 + lrow) * 32 + lko];

  f32x4 acc[4][4] = {};
  for (int k0 = 0; k0 < K; k0 += 32) {
    __syncthreads();
    GL2LDS(ag0, al0); GL2LDS(ag1, al1);
    GL2LDS(bg0, bl0); GL2LDS(bg1, bl1);
    ag0 += 32; ag1 += 32; bg0 += 32; bg1 += 32;
    __syncthreads();
    s16x8 af[4], bf[4];
#pragma unroll
    for (int m = 0; m < 4; ++m) af[m] = *(const s16x8*)(Ars + m * 16 * 32);
#pragma unroll
    for (int n = 0; n < 4; ++n) bf[n] = *(const s16x8*)(Brs + n * 16 * 32);
#pragma unroll
    for (int m = 0; m < 4; ++m)
#pragma unroll
      for (int n = 0; n < 4; ++n)
        acc[m][n] = __builtin_amdgcn_mfma_f32_16x16x32_bf16(af[m], bf[n], acc[m][n], 0, 0, 0);
  }
  const int crow0 = bm * 128 + wm * 64 + (l >> 4) * 4;
  const int ccol0 = bn * 128 + wn * 64 + (l & 15);
#pragma unroll
  for (int m = 0; m < 4; ++m)
#pragma unroll
    for (int rr = 0; rr < 4; ++rr) {
      const int row = crow0 + m * 16 + rr;
      float* cp = Cm + (size_t)row * N + ccol0;
#pragma unroll
      for (int n = 0; n < 4; ++n) cp[n * 16] = acc[m][n][rr];
    }
}

/* ---------------- z-fused bf16-out 128x128 GEMM: per-z (A,B,C,K) table ---------------- */
struct GTab4 {
  const u16* A[4]; const u16* Bm[4]; u16* Cm[4]; int K[4];
};
__global__ void __launch_bounds__(256) gemm128z(GTab4 t, int M, int N) {
  __shared__ u16 As[128 * 32];
  __shared__ u16 Bs[128 * 32];
  const int z = blockIdx.z;
  const u16* A = t.A[z];
  const u16* Bm = t.Bm[z];
  u16* Cm = t.Cm[z];
  const int K = t.K[z];
  const int tid = threadIdx.x;
  const int w = tid >> 6, l = tid & 63;
  const int wm = w >> 1, wn = w & 1;
  const int bm = blockIdx.x, bn = blockIdx.y;

  const int row0 = tid >> 2, kq0 = tid & 3;
  const u16* ag0 = A + (size_t)(bm * 128 + row0) * K + kq0 * 8;
  const u16* ag1 = ag0 + (size_t)64 * K;
  const u16* bg0 = Bm + (size_t)(bn * 128 + row0) * K + kq0 * 8;
  const u16* bg1 = bg0 + (size_t)64 * K;
  u16* al0 = &As[w * 512];
  u16* al1 = &As[2048 + w * 512];
  u16* bl0 = &Bs[w * 512];
  u16* bl1 = &Bs[2048 + w * 512];

  const int lrow = l & 15, lko = (l >> 4) * 8;
  const u16* Ars = &As[(wm * 64 + lrow) * 32 + lko];
  const u16* Brs = &Bs[(wn * 64 + lrow) * 32 + lko];

  f32x4 acc[4][4] = {};
  for (int k0 = 0; k0 < K; k0 += 32) {
    __syncthreads();
    GL2LDS(ag0, al0); GL2LDS(ag1, al1);
    GL2LDS(bg0, bl0); GL2LDS(bg1, bl1);
    ag0 += 32; ag1 += 32; bg0 += 32; bg1 += 32;
    __syncthreads();
    s16x8 af[4], bf[4];
#pragma unroll
    for (int m = 0; m < 4; ++m) af[m] = *(const s16x8*)(Ars + m * 16 * 32);
#pragma unroll
    for (int n = 0; n < 4; ++n) bf[n] = *(const s16x8*)(Brs + n * 16 * 32);
#pragma unroll
    for (int m = 0; m < 4; ++m)
#pragma unroll
      for (int n = 0; n < 4; ++n)
        acc[m][n] = __builtin_amdgcn_mfma_f32_16x16x32_bf16(af[m], bf[n], acc[m][n], 0, 0, 0);
  }
  const int crow0 = bm * 128 + wm * 64 + (l >> 4) * 4;
  const int ccol0 = bn * 128 + wn * 64 + (l & 15);
#pragma unroll
  for (int m = 0; m < 4; ++m)
#pragma unroll
    for (int rr = 0; rr < 4; ++rr) {
      const int row = crow0 + m * 16 + rr;
      u16* cp = Cm + (size_t)row * N + ccol0;
#pragma unroll
      for (int n = 0; n < 4; ++n) cp[n * 16] = f2bf(acc[m][n][rr]);
    }
}

/* ---------------- fused LoRA stage-1: 9 col-groups x split-K 2, fp32 partials ---------------- */
__global__ void __launch_bounds__(256) gemm_lora1(
    const u16* __restrict__ xwb, const u16* __restrict__ xab,
    const u16* __restrict__ xvb, const u16* __restrict__ xgb,
    const u16* __restrict__ w1t, const u16* __restrict__ a1t,
    const u16* __restrict__ v1t, const u16* __restrict__ g1t,
    float* __restrict__ hw, float* __restrict__ ha,
    float* __restrict__ hv, float* __restrict__ hg) {
  __shared__ u16 As[128 * 32];
  __shared__ u16 Bs[32 * 32];
  const int tid = threadIdx.x;
  const int w = tid >> 6, l = tid & 63;
  const int bm = blockIdx.x, g = blockIdx.y, z = blockIdx.z;

  const u16* A; const u16* Bm; float* Cm; int ldc, coloff;
  switch (g) {
    case 0:  A = xwb; Bm = w1t;             Cm = hw; ldc = 64;  coloff = 0;  break;
    case 1:  A = xwb; Bm = w1t + 32 * 2048; Cm = hw; ldc = 64;  coloff = 32; break;
    case 2:  A = xab; Bm = a1t;             Cm = ha; ldc = 64;  coloff = 0;  break;
    case 3:  A = xab; Bm = a1t + 32 * 2048; Cm = ha; ldc = 64;  coloff = 32; break;
    case 4:  A = xvb; Bm = v1t;             Cm = hv; ldc = 32;  coloff = 0;  break;
    default: {
      int gg = g - 5;
      A = xgb; Bm = g1t + (size_t)gg * 32 * 2048; Cm = hg; ldc = 128; coloff = gg * 32;
    }
  }
  A += z * 1024; Bm += z * 1024;
  Cm += (size_t)z * M_ * ldc;

  const int row0 = tid >> 2, kq0 = tid & 3;
  const u16* ag0 = A + (size_t)(bm * 128 + row0) * 2048 + kq0 * 8;
  const u16* ag1 = ag0 + (size_t)64 * 2048;
  u16* al0 = &As[w * 512];
  u16* al1 = &As[2048 + w * 512];
  const int bc = (w & 1) * 64 + l;
  const u16* bg0 = Bm + (size_t)(bc >> 2) * 2048 + (bc & 3) * 8;
  u16* bl0 = &Bs[(w & 1) * 512];

  const int lrow = l & 15, lko = (l >> 4) * 8;
  const u16* Ars = &As[(w * 32 + lrow) * 32 + lko];
  const u16* Brs = &Bs[lrow * 32 + lko];

  f32x4 acc[2][2] = {};
  for (int k0 = 0; k0 < 1024; k0 += 32) {
    __syncthreads();
    GL2LDS(ag0, al0); GL2LDS(ag1, al1);
    if (w < 2) GL2LDS(bg0, bl0);
    ag0 += 32; ag1 += 32; bg0 += 32;
    __syncthreads();
    s16x8 af[2], bf[2];
    af[0] = *(const s16x8*)(Ars);
    af[1] = *(const s16x8*)(Ars + 16 * 32);
    bf[0] = *(const s16x8*)(Brs);
    bf[1] = *(const s16x8*)(Brs + 16 * 32);
#pragma unroll
    for (int m = 0; m < 2; ++m)
#pragma unroll
      for (int n = 0; n < 2; ++n)
        acc[m][n] = __builtin_amdgcn_mfma_f32_16x16x32_bf16(af[m], bf[n], acc[m][n], 0, 0, 0);
  }
  const int crow0 = bm * 128 + w * 32 + (l >> 4) * 4;
  const int ccol0 = coloff + (l & 15);
#pragma unroll
  for (int m = 0; m < 2; ++m)
#pragma unroll
    for (int rr = 0; rr < 4; ++rr) {
      const int row = crow0 + m * 16 + rr;
      float* cp = Cm + (size_t)row * ldc + ccol0;
      cp[0] = acc[m][0][rr];
      cp[16] = acc[m][1][rr];
    }
}

/* ---------------- fused activation: sum 2 partials + act + bf16 ---------------- */
__global__ void __launch_bounds__(256) act_lora(
    const float* __restrict__ hw, const float* __restrict__ ha,
    const float* __restrict__ hv, const float* __restrict__ hg,
    u16* __restrict__ hwb, u16* __restrict__ hab,
    u16* __restrict__ hvb, u16* __restrict__ hgb) {
  int gid = blockIdx.x * 256 + threadIdx.x;
  const int S0 = M_ * 64, S1 = M_ * 64, S2 = M_ * 32, S3 = M_ * 128;
  float v; u16* out; int idx;
  if (gid < S0) { idx = gid; v = tanhf(hw[idx] + hw[idx + S0]); out = hwb; }
  else if (gid < S0 + S1) { idx = gid - S0; v = ha[idx] + ha[idx + S1]; out = hab; }
  else if (gid < S0 + S1 + S2) { idx = gid - S0 - S1; v = hv[idx] + hv[idx + S2]; out = hvb; }
  else { idx = gid - S0 - S1 - S2; v = sigm(hg[idx] + hg[idx + S3]); out = hgb; }
  out[idx] = f2bf(v);
}

/* ---------------- time-shift + 6 token mixes -> bf16 A matrices ---------------- */
__global__ void __launch_bounds__(256) prep_mix(const float* __restrict__ x,
    const float* __restrict__ mr, const float* __restrict__ mw, const float* __restrict__ mk,
    const float* __restrict__ mv, const float* __restrict__ ma, const float* __restrict__ mg,
    u16* __restrict__ xrb, u16* __restrict__ xwb, u16* __restrict__ xkb,
    u16* __restrict__ xvb, u16* __restrict__ xab, u16* __restrict__ xgb) {
  int gid = blockIdx.x * 256 + threadIdx.x;   /* 0 .. MC/8 */
  int row = gid >> 8;
  int col = (gid & 255) << 3;
  size_t base = (size_t)row * C_ + col;
  float xv[8], dx[8];
  *(float4*)&xv[0] = *(const float4*)(x + base);
  *(float4*)&xv[4] = *(const float4*)(x + base + 4);
  if ((row & (T_ - 1)) == 0) {
#pragma unroll
    for (int j = 0; j < 8; ++j) dx[j] = -xv[j];
  } else {
    float xp[8];
    *(float4*)&xp[0] = *(const float4*)(x + base - C_);
    *(float4*)&xp[4] = *(const float4*)(x + base - C_ + 4);
#pragma unroll
    for (int j = 0; j < 8; ++j) dx[j] = xp[j] - xv[j];
  }
#define EMIT(dst, mixp) { \
    float4 m0 = *(const float4*)(mixp + col); \
    float4 m1 = *(const float4*)(mixp + col + 4); \
    float o0 = xv[0] + dx[0] * m0.x, o1 = xv[1] + dx[1] * m0.y; \
    float o2 = xv[2] + dx[2] * m0.z, o3 = xv[3] + dx[3] * m0.w; \
    float o4 = xv[4] + dx[4] * m1.x, o5 = xv[5] + dx[5] * m1.y; \
    float o6 = xv[6] + dx[6] * m1.z, o7 = xv[7] + dx[7] * m1.w; \
    uint4 pk; \
    pk.x = (u32)f2bf(o0) | ((u32)f2bf(o1) << 16); \
    pk.y = (u32)f2bf(o2) | ((u32)f2bf(o3) << 16); \
    pk.z = (u32)f2bf(o4) | ((u32)f2bf(o5) << 16); \
    pk.w = (u32)f2bf(o6) | ((u32)f2bf(o7) << 16); \
    *(uint4*)(dst + base) = pk; }
  EMIT(xrb, mr) EMIT(xwb, mw) EMIT(xkb, mk) EMIT(xvb, mv) EMIT(xab, ma) EMIT(xgb, mg)
#undef EMIT
}

/* ---------------- fused fp32->bf16 weight conversion (4 big square weights) ---------------- */
__global__ void __launch_bounds__(256) convbf8x4(
    const float* __restrict__ i0, const float* __restrict__ i1,
    const float* __restrict__ i2, const float* __restrict__ i3,
    u16* __restrict__ o0, u16* __restrict__ o1, u16* __restrict__ o2, u16* __restrict__ o3) {
  const float* in; u16* out;
  switch (blockIdx.y) {
    case 0: in = i0; out = o0; break;
    case 1: in = i1; out = o1; break;
    case 2: in = i2; out = o2; break;
    default: in = i3; out = o3;
  }
  int gid = blockIdx.x * 256 + threadIdx.x;
  size_t b = (size_t)gid * 8;
  float4 a0 = *(const float4*)(in + b), a1 = *(const float4*)(in + b + 4);
  uint4 pk;
  pk.x = (u32)f2bf(a0.x) | ((u32)f2bf(a0.y) << 16);
  pk.y = (u32)f2bf(a0.z) | ((u32)f2bf(a0.w) << 16);
  pk.z = (u32)f2bf(a1.x) | ((u32)f2bf(a1.y) << 16);
  pk.w = (u32)f2bf(a1.z) | ((u32)f2bf(a1.w) << 16);
  *(uint4*)(out + b) = pk;
}

/* ---------------- fused transpose + bf16 convert (8 LoRA weights) ---------------- */
__global__ void __launch_bounds__(256) tconvbf8(
    const float* __restrict__ w1, const float* __restrict__ a1,
    const float* __restrict__ v1, const float* __restrict__ g1,
    const float* __restrict__ w2, const float* __restrict__ a2,
    const float* __restrict__ v2, const float* __restrict__ g2,
    u16* __restrict__ w1t, u16* __restrict__ a1t, u16* __restrict__ v1t, u16* __restrict__ g1t,
    u16* __restrict__ w2t, u16* __restrict__ a2t, u16* __restrict__ v2t, u16* __restrict__ g2t) {
  const float* in; u16* out; int R, Cc;
  switch (blockIdx.y) {
    case 0: in = w1; out = w1t; R = 2048; Cc = 64; break;
    case 1: in = a1; out = a1t; R = 2048; Cc = 64; break;
    case 2: in = v1; out = v1t; R = 2048; Cc = 32; break;
    case 3: in = g1; out = g1t; R = 2048; Cc = 128; break;
    case 4: in = w2; out = w2t; R = 64; Cc = 2048; break;
    case 5: in = a2; out = a2t; R = 64; Cc = 2048; break;
    case 6: in = v2; out = v2t; R = 32; Cc = 2048; break;
    default: in = g2; out = g2t; R = 128; Cc = 2048;
  }
  int gid = blockIdx.x * 256 + threadIdx.x;
  if (gid >= R * Cc) return;
  int i = gid % R, j = gid / R;
  out[gid] = f2bf(in[(size_t)i * Cc + j]);
}

/* ---------------- scan-prep: decay, kk-norm, k', v-blend, z, b, bonus ---------------- */
__global__ void __launch_bounds__(256) scan_prep(
    const u16* __restrict__ rb, u16* __restrict__ kb, u16* __restrict__ vb,
    const u16* __restrict__ dwb, u16* __restrict__ dab, u16* __restrict__ dvbb,
    const float* __restrict__ v_first,
    const float* __restrict__ a0, const float* __restrict__ v0, const float* __restrict__ w0,
    const float* __restrict__ k_k, const float* __restrict__ k_a, const float* __restrict__ r_k,
    float* __restrict__ dec, u16* __restrict__ bonus) {
  int rh = blockIdx.x * 4 + (threadIdx.x >> 6);
  int n = threadIdx.x & 63;
  int h = rh & (H_ - 1);
  size_t idx = (size_t)rh * 64 + n;
  int c = h * 64 + n;
  float kv = bf2f(kb[idx]), dav = bf2f(dab[idx]), dwv = bf2f(dwb[idx]);
  float dvv = bf2f(dvbb[idx]), vv = bf2f(vb[idx]);
  float vf = v_first[idx], rv = bf2f(rb[idx]);
  float av = sigm(a0[c] + dav);
  float kkv = kv * k_k[c];
  float ss = wsum64(kkv * kkv);
  float kkn = kkv / fmaxf(sqrtf(ss), 1e-12f);
  float k2 = kv * (1.f + (av - 1.f) * k_a[c]);
  float w_ = w0[c] + dwv;
  float wl = -log1pf(expf(-w_)) - 0.5f;
  float decf = expf(-expf(wl));
  float sv = sigm(v0[c] + dvv);
  float v2 = vv + (vf - vv) * sv;
  float bp = wsum64(rv * k2 * r_k[c]);
  kb[idx] = f2bf(k2);
  vb[idx] = f2bf(v2);
  dab[idx] = f2bf(kkn * av);   /* b */
  dvbb[idx] = f2bf(-kkn);      /* z */
  dec[idx] = decf;
  bonus[idx] = f2bf(bp * v2);
}

/* ---------------- RWKV7 chunked scan (WY form), chunk L=16, MFMA ----------------
   Same algorithm as R9 (verified); LDS tiles re-padded to break bank-conflict
   patterns while keeping all b64/b128 accesses 16B-aligned:
     [16][64] u16 -> [16][72] (144B rows, bank-step 4)
     [*][32] u16  -> [*][40]  (80B rows)
   Grid: 256 blocks = 64 heads x 4 value-row slices (16 rows each); 4 waves. */
__global__ void __launch_bounds__(256, 1) rwkv_scan(
    const u16* __restrict__ rb, const float* __restrict__ decb, const u16* __restrict__ kb,
    const u16* __restrict__ vb, const u16* __restrict__ zb, const u16* __restrict__ bbuf,
    float* __restrict__ yb) {
  __shared__ u16 Zt[16][72], Rt[16][72], Bt[16][72], Kt[16][72]; /* [t][j] scaled, bf16 */
  __shared__ u16 BKT[64][40];    /* [j][s]=b~[s][j], [j][16+s]=k~[s][j] */
  __shared__ u16 SAVT[16][40];   /* [i][s]=SA[s][i] (after sub), [i][16+s]=V[s][i0+i] */
  __shared__ u16 MK32[16][40];   /* [t][0..15]=0, [t][16+s]=M_k[t][s] strict-lower */
  __shared__ u16 MRBK[16][40];   /* [t][s]=M_rb tril, [t][16+s]=M_rk tril */
  __shared__ float Mb[16][17];   /* M_b strict-lower fp32 */
  __shared__ float basef[16][17];/* base[t][i] fp32 */
  __shared__ float Ldec[16][64];
  __shared__ float cum[17][68];  /* cum[0]=1, cum[t]=prod d_1..d_t */
  __shared__ float Sf[16][64];   /* state slice fp32 [i][j] */
  __shared__ u16 Sbf[16][72];    /* bf16 copy for MFMA B-operand */

  const int tid = threadIdx.x;
  const int w = tid >> 6, l = tid & 63;
  const int bh = blockIdx.x >> 2;
  const int rblk = blockIdx.x & 3;
  const int bbx = bh >> 5, h = bh & 31;
  const int i0 = rblk * 16;
  const size_t headbase = ((size_t)bbx * T_ * H_ + h) * 64;

  /* zero-init persistent LDS (full padded areas) */
  for (int p = tid; p < 16 * 64; p += 256) ((float*)Sf)[p] = 0.f;
  for (int p = tid; p < 16 * 72; p += 256) ((u16*)Sbf)[p] = 0;
  for (int p = tid; p < 16 * 40; p += 256) { ((u16*)SAVT)[p] = 0; ((u16*)MK32)[p] = 0; }
  __syncthreads();

  /* per-thread staging slot: 4 consecutive elems (t, j..j+3) */
  const int st_ = tid >> 4;
  const int sj = (tid & 15) * 4;
  const size_t g0 = headbase + (size_t)st_ * C_ + sj;

  uint2 cr, ck, cv, cz, cb; float4 cd;
  cr = *(const uint2*)(rb + g0);
  ck = *(const uint2*)(kb + g0);
  cv = *(const uint2*)(vb + g0);
  cz = *(const uint2*)(zb + g0);
  cb = *(const uint2*)(bbuf + g0);
  cd = *(const float4*)(decb + g0);

  const int lrow = l & 15, lko = (l >> 4) * 8;

  for (int ch = 0; ch < T_ / 16; ++ch) {
    /* P0: stage dec */
    *(float4*)&Ldec[st_][sj] = cd;
    __syncthreads();
    /* P1: cumulative decay (wave 0, lane = j) */
    if (w == 0) {
      float c = 1.f;
      cum[0][l] = 1.f;
#pragma unroll
      for (int t = 0; t < 16; ++t) { c *= Ldec[t][l]; cum[t + 1][l] = c; }
    }
    __syncthreads();
    /* P2: scale + write operand matrices; issue next-chunk HBM loads */
    {
      float4 cp = *(const float4*)&cum[st_][sj];
      float4 cc = *(const float4*)&cum[st_ + 1][sj];
      float rv[4], kv[4], zv[4], bv[4];
      rv[0] = bf2f((u16)(cr.x & 0xffff)); rv[1] = bf2f((u16)(cr.x >> 16));
      rv[2] = bf2f((u16)(cr.y & 0xffff)); rv[3] = bf2f((u16)(cr.y >> 16));
      kv[0] = bf2f((u16)(ck.x & 0xffff)); kv[1] = bf2f((u16)(ck.x >> 16));
      kv[2] = bf2f((u16)(ck.y & 0xffff)); kv[3] = bf2f((u16)(ck.y >> 16));
      zv[0] = bf2f((u16)(cz.x & 0xffff)); zv[1] = bf2f((u16)(cz.x >> 16));
      zv[2] = bf2f((u16)(cz.y & 0xffff)); zv[3] = bf2f((u16)(cz.y >> 16));
      bv[0] = bf2f((u16)(cb.x & 0xffff)); bv[1] = bf2f((u16)(cb.x >> 16));
      bv[2] = bf2f((u16)(cb.y & 0xffff)); bv[3] = bf2f((u16)(cb.y >> 16));
      float cpv[4] = {cp.x, cp.y, cp.z, cp.w};
      float ccv[4] = {cc.x, cc.y, cc.z, cc.w};
      u16 zt4[4], rt4[4], bt4[4], kt4[4];
#pragma unroll
      for (int m = 0; m < 4; ++m) {
        float inv = 1.0f / ccv[m];
        zt4[m] = f2bf(zv[m] * cpv[m]);
        rt4[m] = f2bf(rv[m] * ccv[m]);
        bt4[m] = f2bf(bv[m] * inv);
        kt4[m] = f2bf(kv[m] * inv);
      }
      *(uint2*)&Zt[st_][sj] = *(uint2*)zt4;
      *(uint2*)&Rt[st_][sj] = *(uint2*)rt4;
      *(uint2*)&Bt[st_][sj] = *(uint2*)bt4;
      *(uint2*)&Kt[st_][sj] = *(uint2*)kt4;
#pragma unroll
      for (int m = 0; m < 4; ++m) {
        BKT[sj + m][st_] = bt4[m];
        BKT[sj + m][16 + st_] = kt4[m];
      }
      if ((sj >> 4) == rblk) {
        u16 vv4[4];
        vv4[0] = (u16)(cv.x & 0xffff); vv4[1] = (u16)(cv.x >> 16);
        vv4[2] = (u16)(cv.y & 0xffff); vv4[3] = (u16)(cv.y >> 16);
#pragma unroll
        for (int m = 0; m < 4; ++m) SAVT[(sj & 15) + m][16 + st_] = vv4[m];
      }
      if (ch + 1 < T_ / 16) {
        size_t g2 = g0 + (size_t)(ch + 1) * 16 * C_;
        cr = *(const uint2*)(rb + g2);
        ck = *(const uint2*)(kb + g2);
        cv = *(const uint2*)(vb + g2);
        cz = *(const uint2*)(zb + g2);
        cb = *(const uint2*)(bbuf + g2);
        cd = *(const float4*)(decb + g2);
      }
    }
    __syncthreads();
    /* P3: MFMA set A (per-wave) + base/Y part-1.
       w0: M_b = Z~B~^T, keep = Z~S0^T ; w1: M_k = Z~K~^T, keep = R~S0^T ;
       w2: M_rb = R~B~^T ; w3: M_rk = R~K~^T */
    f32x4 keep = {};
    {
      s16x8 a0f, a1f, b0f, b1f;
      if (w == 0 || w == 1) {
        a0f = *(const s16x8*)&Zt[lrow][lko];
        a1f = *(const s16x8*)&Zt[lrow][32 + lko];
      } else {
        a0f = *(const s16x8*)&Rt[lrow][lko];
        a1f = *(const s16x8*)&Rt[lrow][32 + lko];
      }
      if (w == 0 || w == 2) {
        b0f = *(const s16x8*)&Bt[lrow][lko];
        b1f = *(const s16x8*)&Bt[lrow][32 + lko];
      } else {
        b0f = *(const s16x8*)&Kt[lrow][lko];
        b1f = *(const s16x8*)&Kt[lrow][32 + lko];
      }
      f32x4 macc = {};
      macc = __builtin_amdgcn_mfma_f32_16x16x32_bf16(a0f, b0f, macc, 0, 0, 0);
      macc = __builtin_amdgcn_mfma_f32_16x16x32_bf16(a1f, b1f, macc, 0, 0, 0);
      const int s = l & 15;
#pragma unroll
      for (int rr = 0; rr < 4; ++rr) {
        int t = (l >> 4) * 4 + rr;
        float v = macc[rr];
        if (w == 0) Mb[t][s] = (s < t) ? v : 0.f;
        else if (w == 1) MK32[t][16 + s] = f2bf((s < t) ? v : 0.f);
        else if (w == 2) MRBK[t][s] = f2bf((s <= t) ? v : 0.f);
        else MRBK[t][16 + s] = f2bf((s <= t) ? v : 0.f);
      }
      if (w == 0 || w == 1) {
        s16x8 s0f = *(const s16x8*)&Sbf[lrow][lko];
        s16x8 s1f = *(const s16x8*)&Sbf[lrow][32 + lko];
        if (w == 0) {
          keep = __builtin_amdgcn_mfma_f32_16x16x32_bf16(a0f, s0f, keep, 0, 0, 0);
          keep = __builtin_amdgcn_mfma_f32_16x16x32_bf16(a1f, s1f, keep, 0, 0, 0);
        } else {
          s16x8 ra0 = *(const s16x8*)&Rt[lrow][lko];
          s16x8 ra1 = *(const s16x8*)&Rt[lrow][32 + lko];
          keep = __builtin_amdgcn_mfma_f32_16x16x32_bf16(ra0, s0f, keep, 0, 0, 0);
          keep = __builtin_amdgcn_mfma_f32_16x16x32_bf16(ra1, s1f, keep, 0, 0, 0);
        }
      }
    }
    __syncthreads();
    /* P4+P5: wave0: base += [0|M_k] x SAVT ; forward substitution -> SA */
    if (w == 0) {
      s16x8 af = *(const s16x8*)&MK32[lrow][lko];
      s16x8 bf = *(const s16x8*)&SAVT[lrow][lko];
      keep = __builtin_amdgcn_mfma_f32_16x16x32_bf16(af, bf, keep, 0, 0, 0);
      const int i = l & 15;
#pragma unroll
      for (int rr = 0; rr < 4; ++rr) basef[(l >> 4) * 4 + rr][i] = keep[rr];
      float sa[16];
#pragma unroll
      for (int t = 0; t < 16; ++t) {
        float acc = basef[t][i];
#pragma unroll
        for (int s = 0; s < 16; ++s) {
          if (s < t) acc += Mb[t][s] * sa[s];
        }
        sa[t] = acc;
      }
      if (l < 16) {
        u32* dst = (u32*)&SAVT[l][0];
#pragma unroll
        for (int m = 0; m < 8; ++m)
          dst[m] = (u32)f2bf(sa[2 * m]) | ((u32)f2bf(sa[2 * m + 1]) << 16);
      }
    }
    __syncthreads();
    /* P6: Y finish + store (wave1); state update (all waves, one j-tile each) */
    if (w == 1) {
      s16x8 af = *(const s16x8*)&MRBK[lrow][lko];
      s16x8 bf = *(const s16x8*)&SAVT[lrow][lko];
      f32x4 yacc = __builtin_amdgcn_mfma_f32_16x16x32_bf16(af, bf, keep, 0, 0, 0);
#pragma unroll
      for (int rr = 0; rr < 4; ++rr) {
        int t = (l >> 4) * 4 + rr;
        yb[headbase + (size_t)(ch * 16 + t) * C_ + i0 + (l & 15)] = yacc[rr];
      }
    }
    {
      const int j0 = w * 16;
      s16x8 af = *(const s16x8*)&SAVT[lrow][lko];
      s16x8 bf = *(const s16x8*)&BKT[j0 + lrow][lko];
      f32x4 up = {};
      up = __builtin_amdgcn_mfma_f32_16x16x32_bf16(af, bf, up, 0, 0, 0);
      const int j = j0 + (l & 15);
      float cl = cum[16][j];
#pragma unroll
      for (int rr = 0; rr < 4; ++rr) {
        int i = (l >> 4) * 4 + rr;
        float sn = (Sf[i][j] + up[rr]) * cl;
        Sf[i][j] = sn;
        Sbf[i][j] = f2bf(sn);
      }
    }
    __syncthreads();
  }
}

/* ---------------- GroupNorm(64/head) + bonus + gate -> bf16 A for final GEMM ---------------- */
__global__ void __launch_bounds__(256) gn_gg(
    const float* __restrict__ yb, const u16* __restrict__ bonus, const u16* __restrict__ gb,
    const float* __restrict__ gnw, const float* __restrict__ gnb,
    u16* __restrict__ ggb) {
  int rh = blockIdx.x * 4 + (threadIdx.x >> 6);
  int n = threadIdx.x & 63;
  int h = rh & (H_ - 1);
  size_t idx = (size_t)rh * 64 + n;
  int c = h * 64 + n;
  float y = yb[idx];
  float mu = wsum64(y) * (1.f / 64.f);
  float d = y - mu;
  float var = wsum64(d * d) * (1.f / 64.f);
  float yn = d * rsqrtf(var + 6.4e-4f) * gnw[c] + gnb[c];
  ggb[idx] = f2bf((yn + bf2f(bonus[idx])) * bf2f(gb[idx]));
}

extern "C" void kernel_launch(void* const* d_in, const int* in_sizes, int n_in,
                              void* d_out, int out_size, void* d_ws, size_t ws_size,
                              hipStream_t stream) {
  const float* x      = (const float*)d_in[0];
  const float* vfirst = (const float*)d_in[1];
  const float* x_r = (const float*)d_in[2];
  const float* x_w = (const float*)d_in[3];
  const float* x_k = (const float*)d_in[4];
  const float* x_v = (const float*)d_in[5];
  const float* x_a = (const float*)d_in[6];
  const float* x_g = (const float*)d_in[7];
  const float* w0  = (const float*)d_in[8];
  const float* w1  = (const float*)d_in[9];
  const float* w2  = (const float*)d_in[10];
  const float* a0  = (const float*)d_in[11];
  const float* a1  = (const float*)d_in[12];
  const float* a2  = (const float*)d_in[13];
  const float* v0  = (const float*)d_in[14];
  const float* v1  = (const float*)d_in[15];
  const float* v2  = (const float*)d_in[16];
  const float* g1  = (const float*)d_in[17];
  const float* g2  = (const float*)d_in[18];
  const float* k_k = (const float*)d_in[19];
  const float* k_a = (const float*)d_in[20];
  const float* r_k = (const float*)d_in[21];
  const float* W_r = (const float*)d_in[22];
  const float* W_k = (const float*)d_in[23];
  const float* W_v = (const float*)d_in[24];
  const float* W_o = (const float*)d_in[25];
  const float* gnw = (const float*)d_in[26];
  const float* gnb = (const float*)d_in[27];
  float* out = (float*)d_out;

  char* ws = (char*)d_ws;
  size_t off = 0;
  auto alloc = [&](size_t bytes) -> void* {
    void* p = ws + off;
    off += (bytes + 255) & ~(size_t)255;
    return p;
  };
  const size_t MCb2 = MC * 2;

  /* A-region: 6 contiguous 16MiB bf16 mix buffers, later reused */
  u16* xrb = (u16*)alloc(MCb2);   /* A0: xr -> dw_bf -> ggb            */
  u16* xwb = (u16*)alloc(MCb2);   /* A1: xw -> da_bf -> b_bf           */
  u16* xkb = (u16*)alloc(MCb2);   /* A2: xk -> dv_bf -> z_bf           */
  u16* xvb = (u16*)alloc(MCb2);   /* A3: xv -> g_bf                    */
  u16* xab = (u16*)alloc(MCb2);   /* A4: xa ┐                          */
  u16* xgb = (u16*)alloc(MCb2);   /* A5: xg ┘ -> yb fp32 (32MiB)       */
  u16* Wrb = (u16*)alloc((size_t)C_ * C_ * 2);
  u16* Wkb = (u16*)alloc((size_t)C_ * C_ * 2);
  u16* Wvb = (u16*)alloc((size_t)C_ * C_ * 2);
  u16* Wob = (u16*)alloc((size_t)C_ * C_ * 2);
  u16* w1t = (u16*)alloc((size_t)64 * C_ * 2);
  u16* a1t = (u16*)alloc((size_t)64 * C_ * 2);
  u16* v1t = (u16*)alloc((size_t)32 * C_ * 2);
  u16* g1t = (u16*)alloc((size_t)128 * C_ * 2);
  u16* w2t = (u16*)alloc((size_t)C_ * 64 * 2);
  u16* a2t = (u16*)alloc((size_t)C_ * 64 * 2);
  u16* v2t = (u16*)alloc((size_t)C_ * 32 * 2);
  u16* g2t = (u16*)alloc((size_t)C_ * 128 * 2);
  float* hw = (float*)alloc((size_t)M_ * 64 * 4 * 2);   /* 2 split-K partials */
  float* ha = (float*)alloc((size_t)M_ * 64 * 4 * 2);
  float* hv = (float*)alloc((size_t)M_ * 32 * 4 * 2);
  float* hg = (float*)alloc((size_t)M_ * 128 * 4 * 2);
  u16* hwb = (u16*)alloc((size_t)M_ * 64 * 2);
  u16* hab = (u16*)alloc((size_t)M_ * 64 * 2);
  u16* hvb = (u16*)alloc((size_t)M_ * 32 * 2);
  u16* hgb = (u16*)alloc((size_t)M_ * 128 * 2);
  u16* r_bf = (u16*)alloc(MCb2);            /* D0 */
  u16* k_bf = (u16*)alloc(MCb2);            /* D1: k -> k2 in place */
  u16* v_bf = (u16*)alloc(MCb2);            /* D2: v -> v2 in place */
  float* dec = (float*)alloc(MC * 4);       /* E0 fp32 */
  u16* bonus  = (u16*)alloc(MCb2);          /* E1 */
  /* aliases (regions dead at write time; see schedule) */
  u16* dw_bf = xrb;
  u16* da_bf = xwb;
  u16* dv_bf = xkb;
  u16* g_bf  = xvb;
  float* yb  = (float*)xab;  /* spans xab+xgb = 32 MiB */
  u16* ggb   = xrb;          /* after dw_bf consumed   */
  (void)ws_size; (void)in_sizes; (void)n_in; (void)out_size;

  dim3 blk(256);

  /* weight conversion: 2 fused launches */
  convbf8x4<<<dim3(C_ * C_ / 8 / 256, 4), blk, 0, stream>>>(W_r, W_k, W_v, W_o, Wrb, Wkb, Wvb, Wob);
  tconvbf8<<<dim3(1024, 8), blk, 0, stream>>>(w1, a1, v1, g1, w2, a2, v2, g2,
                                              w1t, a1t, v1t, g1t, w2t, a2t, v2t, g2t);

  /* time-shift mixes, v_first passthrough */
  prep_mix<<<(int)(MC / 8 / 256), blk, 0, stream>>>(x, x_r, x_w, x_k, x_v, x_a, x_g,
                                                    xrb, xwb, xkb, xvb, xab, xgb);
  hipMemcpyAsync(out + MC, vfirst, MC * sizeof(float), hipMemcpyDeviceToDevice, stream);

  /* big GEMMs r,k,v: one fused launch */
  {
    GTab4 t;
    t.A[0] = xrb; t.Bm[0] = Wrb; t.Cm[0] = r_bf; t.K[0] = 2048;
    t.A[1] = xkb; t.Bm[1] = Wkb; t.Cm[1] = k_bf; t.K[1] = 2048;
    t.A[2] = xvb; t.Bm[2] = Wvb; t.Cm[2] = v_bf; t.K[2] = 2048;
    t.A[3] = xrb; t.Bm[3] = Wrb; t.Cm[3] = r_bf; t.K[3] = 2048;
    gemm128z<<<dim3(M_ / 128, C_ / 128, 3), blk, 0, stream>>>(t, M_, C_);
  }

  /* LoRA stage-1: fused, split-K 2 -> fp32 partials */
  gemm_lora1<<<dim3(M_ / 128, 9, 2), blk, 0, stream>>>(xwb, xab, xvb, xgb,
                                                       w1t, a1t, v1t, g1t,
                                                       hw, ha, hv, hg);

  /* fused activation + partial-sum + bf16 */
  act_lora<<<dim3(M_ * 288 / 256), blk, 0, stream>>>(hw, ha, hv, hg, hwb, hab, hvb, hgb);

  /* LoRA stage-2: one fused launch (bf16 out, into dead mix regions) */
  {
    GTab4 t;
    t.A[0] = hwb; t.Bm[0] = w2t; t.Cm[0] = dw_bf; t.K[0] = 64;
    t.A[1] = hab; t.Bm[1] = a2t; t.Cm[1] = da_bf; t.K[1] = 64;
    t.A[2] = hvb; t.Bm[2] = v2t; t.Cm[2] = dv_bf; t.K[2] = 32;
    t.A[3] = hgb; t.Bm[3] = g2t; t.Cm[3] = g_bf;  t.K[3] = 128;
    gemm128z<<<dim3(M_ / 128, C_ / 128, 4), blk, 0, stream>>>(t, M_, C_);
  }

  /* scan inputs (in-place bf16) + dec fp32 + bonus bf16 */
  scan_prep<<<M_ * H_ / 4, blk, 0, stream>>>(r_bf, k_bf, v_bf, dw_bf, da_bf, dv_bf, vfirst,
                                             a0, v0, w0, k_k, k_a, r_k, dec, bonus);

  /* chunked scan: 256 blocks (64 heads x 4 row-slices) x 256 threads */
  rwkv_scan<<<dim3(256), dim3(256), 0, stream>>>(r_bf, dec, k_bf, v_bf, dv_bf, da_bf, yb);

  /* GroupNorm + bonus + gate -> bf16 */
  gn_gg<<<M_ * H_ / 4, blk, 0, stream>>>(yb, bonus, g_bf, gnw, gnb, ggb);

  /* output projection (fp32 out) */
  gemm128f<<<dim3(M_ / 128, C_ / 128), blk, 0, stream>>>(ggb, Wob, out, M_, C_, C_);
}

// Round 11
// 700.149 us; speedup vs baseline: 1.8094x; 1.0068x over previous
//
#include <hip/hip_runtime.h>
#include <stdint.h>

typedef unsigned short u16;
typedef unsigned int u32;

#define B_ 2
#define T_ 2048
#define C_ 2048
#define H_ 32
#define M_ (B_*T_)              /* 4096 rows */
static const size_t MC = (size_t)M_ * C_;   /* 8388608 */

typedef __attribute__((ext_vector_type(8))) short s16x8;
typedef __attribute__((ext_vector_type(4))) float f32x4;

__device__ __forceinline__ u16 f2bf(float f) {
  union { float f; u32 u; } v; v.f = f;
  u32 r = v.u + 0x7FFFu + ((v.u >> 16) & 1u);
  return (u16)(r >> 16);
}
__device__ __forceinline__ float bits2f(u32 u) {
  union { u32 u; float f; } v; v.u = u; return v.f;
}
__device__ __forceinline__ float bf2f(u16 h) { return bits2f(((u32)h) << 16); }
__device__ __forceinline__ float sigm(float x) { return 1.0f / (1.0f + expf(-x)); }

__device__ __forceinline__ float wsum64(float x) {
  x += __shfl_xor(x, 32);
  x += __shfl_xor(x, 16);
  x += __shfl_xor(x, 8);
  x += __shfl_xor(x, 4);
  x += __shfl_xor(x, 2);
  x += __shfl_xor(x, 1);
  return x;
}

#define GL2LDS(g, l) __builtin_amdgcn_global_load_lds( \
    (const __attribute__((address_space(1))) u32*)(g), \
    (__attribute__((address_space(3))) u32*)(l), 16, 0, 0)

/* ---------------- bf16 NT GEMM, 128x128 tile, BK=32; fp32 C (W_o) ---------------- */
__global__ void __launch_bounds__(256) gemm128f(const u16* __restrict__ A, const u16* __restrict__ Bm,
                                                float* __restrict__ Cm, int M, int N, int K) {
  __shared__ u16 As[128 * 32];
  __shared__ u16 Bs[128 * 32];
  const int tid = threadIdx.x;
  const int w = tid >> 6, l = tid & 63;
  const int wm = w >> 1, wn = w & 1;
  const int bm = blockIdx.x, bn = blockIdx.y;

  const int row0 = tid >> 2, kq0 = tid & 3;
  const u16* ag0 = A + (size_t)(bm * 128 + row0) * K + kq0 * 8;
  const u16* ag1 = ag0 + (size_t)64 * K;
  const u16* bg0 = Bm + (size_t)(bn * 128 + row0) * K + kq0 * 8;
  const u16* bg1 = bg0 + (size_t)64 * K;
  u16* al0 = &As[w * 512];
  u16* al1 = &As[2048 + w * 512];
  u16* bl0 = &Bs[w * 512];
  u16* bl1 = &Bs[2048 + w * 512];

  const int lrow = l & 15, lko = (l >> 4) * 8;
  const u16* Ars = &As[(wm * 64 + lrow) * 32 + lko];
  const u16* Brs = &Bs[(wn * 64 + lrow) * 32 + lko];

  f32x4 acc[4][4] = {};
  for (int k0 = 0; k0 < K; k0 += 32) {
    __syncthreads();
    GL2LDS(ag0, al0); GL2LDS(ag1, al1);
    GL2LDS(bg0, bl0); GL2LDS(bg1, bl1);
    ag0 += 32; ag1 += 32; bg0 += 32; bg1 += 32;
    __syncthreads();
    s16x8 af[4], bf[4];
#pragma unroll
    for (int m = 0; m < 4; ++m) af[m] = *(const s16x8*)(Ars + m * 16 * 32);
#pragma unroll
    for (int n = 0; n < 4; ++n) bf[n] = *(const s16x8*)(Brs + n * 16 * 32);
#pragma unroll
    for (int m = 0; m < 4; ++m)
#pragma unroll
      for (int n = 0; n < 4; ++n)
        acc[m][n] = __builtin_amdgcn_mfma_f32_16x16x32_bf16(af[m], bf[n], acc[m][n], 0, 0, 0);
  }
  const int crow0 = bm * 128 + wm * 64 + (l >> 4) * 4;
  const int ccol0 = bn * 128 + wn * 64 + (l & 15);
#pragma unroll
  for (int m = 0; m < 4; ++m)
#pragma unroll
    for (int rr = 0; rr < 4; ++rr) {
      const int row = crow0 + m * 16 + rr;
      float* cp = Cm + (size_t)row * N + ccol0;
#pragma unroll
      for (int n = 0; n < 4; ++n) cp[n * 16] = acc[m][n][rr];
    }
}

/* ---------------- z-fused bf16-out 128x128 GEMM: per-z (A,B,C,K) table ---------------- */
struct GTab4 {
  const u16* A[4]; const u16* Bm[4]; u16* Cm[4]; int K[4];
};
__global__ void __launch_bounds__(256) gemm128z(GTab4 t, int M, int N) {
  __shared__ u16 As[128 * 32];
  __shared__ u16 Bs[128 * 32];
  const int z = blockIdx.z;
  const u16* A = t.A[z];
  const u16* Bm = t.Bm[z];
  u16* Cm = t.Cm[z];
  const int K = t.K[z];
  const int tid = threadIdx.x;
  const int w = tid >> 6, l = tid & 63;
  const int wm = w >> 1, wn = w & 1;
  const int bm = blockIdx.x, bn = blockIdx.y;

  const int row0 = tid >> 2, kq0 = tid & 3;
  const u16* ag0 = A + (size_t)(bm * 128 + row0) * K + kq0 * 8;
  const u16* ag1 = ag0 + (size_t)64 * K;
  const u16* bg0 = Bm + (size_t)(bn * 128 + row0) * K + kq0 * 8;
  const u16* bg1 = bg0 + (size_t)64 * K;
  u16* al0 = &As[w * 512];
  u16* al1 = &As[2048 + w * 512];
  u16* bl0 = &Bs[w * 512];
  u16* bl1 = &Bs[2048 + w * 512];

  const int lrow = l & 15, lko = (l >> 4) * 8;
  const u16* Ars = &As[(wm * 64 + lrow) * 32 + lko];
  const u16* Brs = &Bs[(wn * 64 + lrow) * 32 + lko];

  f32x4 acc[4][4] = {};
  for (int k0 = 0; k0 < K; k0 += 32) {
    __syncthreads();
    GL2LDS(ag0, al0); GL2LDS(ag1, al1);
    GL2LDS(bg0, bl0); GL2LDS(bg1, bl1);
    ag0 += 32; ag1 += 32; bg0 += 32; bg1 += 32;
    __syncthreads();
    s16x8 af[4], bf[4];
#pragma unroll
    for (int m = 0; m < 4; ++m) af[m] = *(const s16x8*)(Ars + m * 16 * 32);
#pragma unroll
    for (int n = 0; n < 4; ++n) bf[n] = *(const s16x8*)(Brs + n * 16 * 32);
#pragma unroll
    for (int m = 0; m < 4; ++m)
#pragma unroll
      for (int n = 0; n < 4; ++n)
        acc[m][n] = __builtin_amdgcn_mfma_f32_16x16x32_bf16(af[m], bf[n], acc[m][n], 0, 0, 0);
  }
  const int crow0 = bm * 128 + wm * 64 + (l >> 4) * 4;
  const int ccol0 = bn * 128 + wn * 64 + (l & 15);
#pragma unroll
  for (int m = 0; m < 4; ++m)
#pragma unroll
    for (int rr = 0; rr < 4; ++rr) {
      const int row = crow0 + m * 16 + rr;
      u16* cp = Cm + (size_t)row * N + ccol0;
#pragma unroll
      for (int n = 0; n < 4; ++n) cp[n * 16] = f2bf(acc[m][n][rr]);
    }
}

/* ---------------- fused LoRA stage-1: 9 col-groups x split-K 2, fp32 partials ---------------- */
__global__ void __launch_bounds__(256) gemm_lora1(
    const u16* __restrict__ xwb, const u16* __restrict__ xab,
    const u16* __restrict__ xvb, const u16* __restrict__ xgb,
    const u16* __restrict__ w1t, const u16* __restrict__ a1t,
    const u16* __restrict__ v1t, const u16* __restrict__ g1t,
    float* __restrict__ hw, float* __restrict__ ha,
    float* __restrict__ hv, float* __restrict__ hg) {
  __shared__ u16 As[128 * 32];
  __shared__ u16 Bs[32 * 32];
  const int tid = threadIdx.x;
  const int w = tid >> 6, l = tid & 63;
  const int bm = blockIdx.x, g = blockIdx.y, z = blockIdx.z;

  const u16* A; const u16* Bm; float* Cm; int ldc, coloff;
  switch (g) {
    case 0:  A = xwb; Bm = w1t;             Cm = hw; ldc = 64;  coloff = 0;  break;
    case 1:  A = xwb; Bm = w1t + 32 * 2048; Cm = hw; ldc = 64;  coloff = 32; break;
    case 2:  A = xab; Bm = a1t;             Cm = ha; ldc = 64;  coloff = 0;  break;
    case 3:  A = xab; Bm = a1t + 32 * 2048; Cm = ha; ldc = 64;  coloff = 32; break;
    case 4:  A = xvb; Bm = v1t;             Cm = hv; ldc = 32;  coloff = 0;  break;
    default: {
      int gg = g - 5;
      A = xgb; Bm = g1t + (size_t)gg * 32 * 2048; Cm = hg; ldc = 128; coloff = gg * 32;
    }
  }
  A += z * 1024; Bm += z * 1024;
  Cm += (size_t)z * M_ * ldc;

  const int row0 = tid >> 2, kq0 = tid & 3;
  const u16* ag0 = A + (size_t)(bm * 128 + row0) * 2048 + kq0 * 8;
  const u16* ag1 = ag0 + (size_t)64 * 2048;
  u16* al0 = &As[w * 512];
  u16* al1 = &As[2048 + w * 512];
  const int bc = (w & 1) * 64 + l;
  const u16* bg0 = Bm + (size_t)(bc >> 2) * 2048 + (bc & 3) * 8;
  u16* bl0 = &Bs[(w & 1) * 512];

  const int lrow = l & 15, lko = (l >> 4) * 8;
  const u16* Ars = &As[(w * 32 + lrow) * 32 + lko];
  const u16* Brs = &Bs[lrow * 32 + lko];

  f32x4 acc[2][2] = {};
  for (int k0 = 0; k0 < 1024; k0 += 32) {
    __syncthreads();
    GL2LDS(ag0, al0); GL2LDS(ag1, al1);
    if (w < 2) GL2LDS(bg0, bl0);
    ag0 += 32; ag1 += 32; bg0 += 32;
    __syncthreads();
    s16x8 af[2], bf[2];
    af[0] = *(const s16x8*)(Ars);
    af[1] = *(const s16x8*)(Ars + 16 * 32);
    bf[0] = *(const s16x8*)(Brs);
    bf[1] = *(const s16x8*)(Brs + 16 * 32);
#pragma unroll
    for (int m = 0; m < 2; ++m)
#pragma unroll
      for (int n = 0; n < 2; ++n)
        acc[m][n] = __builtin_amdgcn_mfma_f32_16x16x32_bf16(af[m], bf[n], acc[m][n], 0, 0, 0);
  }
  const int crow0 = bm * 128 + w * 32 + (l >> 4) * 4;
  const int ccol0 = coloff + (l & 15);
#pragma unroll
  for (int m = 0; m < 2; ++m)
#pragma unroll
    for (int rr = 0; rr < 4; ++rr) {
      const int row = crow0 + m * 16 + rr;
      float* cp = Cm + (size_t)row * ldc + ccol0;
      cp[0] = acc[m][0][rr];
      cp[16] = acc[m][1][rr];
    }
}

/* ---------------- fused activation: sum 2 partials + act + bf16 ---------------- */
__global__ void __launch_bounds__(256) act_lora(
    const float* __restrict__ hw, const float* __restrict__ ha,
    const float* __restrict__ hv, const float* __restrict__ hg,
    u16* __restrict__ hwb, u16* __restrict__ hab,
    u16* __restrict__ hvb, u16* __restrict__ hgb) {
  int gid = blockIdx.x * 256 + threadIdx.x;
  const int S0 = M_ * 64, S1 = M_ * 64, S2 = M_ * 32, S3 = M_ * 128;
  float v; u16* out; int idx;
  if (gid < S0) { idx = gid; v = tanhf(hw[idx] + hw[idx + S0]); out = hwb; }
  else if (gid < S0 + S1) { idx = gid - S0; v = ha[idx] + ha[idx + S1]; out = hab; }
  else if (gid < S0 + S1 + S2) { idx = gid - S0 - S1; v = hv[idx] + hv[idx + S2]; out = hvb; }
  else { idx = gid - S0 - S1 - S2; v = sigm(hg[idx] + hg[idx + S3]); out = hgb; }
  out[idx] = f2bf(v);
}

/* ---------------- time-shift + 6 token mixes -> bf16 A matrices ---------------- */
__global__ void __launch_bounds__(256) prep_mix(const float* __restrict__ x,
    const float* __restrict__ mr, const float* __restrict__ mw, const float* __restrict__ mk,
    const float* __restrict__ mv, const float* __restrict__ ma, const float* __restrict__ mg,
    u16* __restrict__ xrb, u16* __restrict__ xwb, u16* __restrict__ xkb,
    u16* __restrict__ xvb, u16* __restrict__ xab, u16* __restrict__ xgb) {
  int gid = blockIdx.x * 256 + threadIdx.x;   /* 0 .. MC/8 */
  int row = gid >> 8;
  int col = (gid & 255) << 3;
  size_t base = (size_t)row * C_ + col;
  float xv[8], dx[8];
  *(float4*)&xv[0] = *(const float4*)(x + base);
  *(float4*)&xv[4] = *(const float4*)(x + base + 4);
  if ((row & (T_ - 1)) == 0) {
#pragma unroll
    for (int j = 0; j < 8; ++j) dx[j] = -xv[j];
  } else {
    float xp[8];
    *(float4*)&xp[0] = *(const float4*)(x + base - C_);
    *(float4*)&xp[4] = *(const float4*)(x + base - C_ + 4);
#pragma unroll
    for (int j = 0; j < 8; ++j) dx[j] = xp[j] - xv[j];
  }
#define EMIT(dst, mixp) { \
    float4 m0 = *(const float4*)(mixp + col); \
    float4 m1 = *(const float4*)(mixp + col + 4); \
    float o0 = xv[0] + dx[0] * m0.x, o1 = xv[1] + dx[1] * m0.y; \
    float o2 = xv[2] + dx[2] * m0.z, o3 = xv[3] + dx[3] * m0.w; \
    float o4 = xv[4] + dx[4] * m1.x, o5 = xv[5] + dx[5] * m1.y; \
    float o6 = xv[6] + dx[6] * m1.z, o7 = xv[7] + dx[7] * m1.w; \
    uint4 pk; \
    pk.x = (u32)f2bf(o0) | ((u32)f2bf(o1) << 16); \
    pk.y = (u32)f2bf(o2) | ((u32)f2bf(o3) << 16); \
    pk.z = (u32)f2bf(o4) | ((u32)f2bf(o5) << 16); \
    pk.w = (u32)f2bf(o6) | ((u32)f2bf(o7) << 16); \
    *(uint4*)(dst + base) = pk; }
  EMIT(xrb, mr) EMIT(xwb, mw) EMIT(xkb, mk) EMIT(xvb, mv) EMIT(xab, ma) EMIT(xgb, mg)
#undef EMIT
}

/* ---------------- fused fp32->bf16 weight conversion (4 big square weights) ---------------- */
__global__ void __launch_bounds__(256) convbf8x4(
    const float* __restrict__ i0, const float* __restrict__ i1,
    const float* __restrict__ i2, const float* __restrict__ i3,
    u16* __restrict__ o0, u16* __restrict__ o1, u16* __restrict__ o2, u16* __restrict__ o3) {
  const float* in; u16* out;
  switch (blockIdx.y) {
    case 0: in = i0; out = o0; break;
    case 1: in = i1; out = o1; break;
    case 2: in = i2; out = o2; break;
    default: in = i3; out = o3;
  }
  int gid = blockIdx.x * 256 + threadIdx.x;
  size_t b = (size_t)gid * 8;
  float4 a0 = *(const float4*)(in + b), a1 = *(const float4*)(in + b + 4);
  uint4 pk;
  pk.x = (u32)f2bf(a0.x) | ((u32)f2bf(a0.y) << 16);
  pk.y = (u32)f2bf(a0.z) | ((u32)f2bf(a0.w) << 16);
  pk.z = (u32)f2bf(a1.x) | ((u32)f2bf(a1.y) << 16);
  pk.w = (u32)f2bf(a1.z) | ((u32)f2bf(a1.w) << 16);
  *(uint4*)(out + b) = pk;
}

/* ---------------- fused transpose + bf16 convert (8 LoRA weights) ---------------- */
__global__ void __launch_bounds__(256) tconvbf8(
    const float* __restrict__ w1, const float* __restrict__ a1,
    const float* __restrict__ v1, const float* __restrict__ g1,
    const float* __restrict__ w2, const float* __restrict__ a2,
    const float* __restrict__ v2, const float* __restrict__ g2,
    u16* __restrict__ w1t, u16* __restrict__ a1t, u16* __restrict__ v1t, u16* __restrict__ g1t,
    u16* __restrict__ w2t, u16* __restrict__ a2t, u16* __restrict__ v2t, u16* __restrict__ g2t) {
  const float* in; u16* out; int R, Cc;
  switch (blockIdx.y) {
    case 0: in = w1; out = w1t; R = 2048; Cc = 64; break;
    case 1: in = a1; out = a1t; R = 2048; Cc = 64; break;
    case 2: in = v1; out = v1t; R = 2048; Cc = 32; break;
    case 3: in = g1; out = g1t; R = 2048; Cc = 128; break;
    case 4: in = w2; out = w2t; R = 64; Cc = 2048; break;
    case 5: in = a2; out = a2t; R = 64; Cc = 2048; break;
    case 6: in = v2; out = v2t; R = 32; Cc = 2048; break;
    default: in = g2; out = g2t; R = 128; Cc = 2048;
  }
  int gid = blockIdx.x * 256 + threadIdx.x;
  if (gid >= R * Cc) return;
  int i = gid % R, j = gid / R;
  out[gid] = f2bf(in[(size_t)i * Cc + j]);
}

/* ---------------- scan-prep: decay, kk-norm, k', v-blend, z, b, bonus ---------------- */
__global__ void __launch_bounds__(256) scan_prep(
    const u16* __restrict__ rb, u16* __restrict__ kb, u16* __restrict__ vb,
    const u16* __restrict__ dwb, u16* __restrict__ dab, u16* __restrict__ dvbb,
    const float* __restrict__ v_first,
    const float* __restrict__ a0, const float* __restrict__ v0, const float* __restrict__ w0,
    const float* __restrict__ k_k, const float* __restrict__ k_a, const float* __restrict__ r_k,
    float* __restrict__ dec, u16* __restrict__ bonus) {
  int rh = blockIdx.x * 4 + (threadIdx.x >> 6);
  int n = threadIdx.x & 63;
  int h = rh & (H_ - 1);
  size_t idx = (size_t)rh * 64 + n;
  int c = h * 64 + n;
  float kv = bf2f(kb[idx]), dav = bf2f(dab[idx]), dwv = bf2f(dwb[idx]);
  float dvv = bf2f(dvbb[idx]), vv = bf2f(vb[idx]);
  float vf = v_first[idx], rv = bf2f(rb[idx]);
  float av = sigm(a0[c] + dav);
  float kkv = kv * k_k[c];
  float ss = wsum64(kkv * kkv);
  float kkn = kkv / fmaxf(sqrtf(ss), 1e-12f);
  float k2 = kv * (1.f + (av - 1.f) * k_a[c]);
  float w_ = w0[c] + dwv;
  float wl = -log1pf(expf(-w_)) - 0.5f;
  float decf = expf(-expf(wl));
  float sv = sigm(v0[c] + dvv);
  float v2 = vv + (vf - vv) * sv;
  float bp = wsum64(rv * k2 * r_k[c]);
  kb[idx] = f2bf(k2);
  vb[idx] = f2bf(v2);
  dab[idx] = f2bf(kkn * av);   /* b */
  dvbb[idx] = f2bf(-kkn);      /* z */
  dec[idx] = decf;
  bonus[idx] = f2bf(bp * v2);
}

/* ---------------- RWKV7 chunked scan (WY form), chunk L=16, MFMA ----------------
   R9/R10 algorithm; R11 changes: blocked forward substitution (4x4),
   P0 barrier eliminated (Ldec staged in P6 of previous chunk),
   Ldec/Sf padded to 68-word rows, Mb/basef to [16][20]. */
__global__ void __launch_bounds__(256, 1) rwkv_scan(
    const u16* __restrict__ rb, const float* __restrict__ decb, const u16* __restrict__ kb,
    const u16* __restrict__ vb, const u16* __restrict__ zb, const u16* __restrict__ bbuf,
    float* __restrict__ yb) {
  __shared__ u16 Zt[16][72], Rt[16][72], Bt[16][72], Kt[16][72]; /* [t][j] scaled, bf16 */
  __shared__ u16 BKT[64][40];    /* [j][s]=b~[s][j], [j][16+s]=k~[s][j] */
  __shared__ u16 SAVT[16][40];   /* [i][s]=SA[s][i] (after sub), [i][16+s]=V[s][i0+i] */
  __shared__ u16 MK32[16][40];   /* [t][0..15]=0, [t][16+s]=M_k[t][s] strict-lower */
  __shared__ u16 MRBK[16][40];   /* [t][s]=M_rb tril, [t][16+s]=M_rk tril */
  __shared__ float Mb[16][20];   /* M_b strict-lower fp32, float4-aligned rows */
  __shared__ float basef[16][20];/* base[t][i] fp32 */
  __shared__ float Ldec[16][68];
  __shared__ float cum[17][68];  /* cum[0]=1, cum[t]=prod d_1..d_t */
  __shared__ float Sf[16][68];   /* state slice fp32 [i][j] */
  __shared__ u16 Sbf[16][72];    /* bf16 copy for MFMA B-operand */

  const int tid = threadIdx.x;
  const int w = tid >> 6, l = tid & 63;
  const int bh = blockIdx.x >> 2;
  const int rblk = blockIdx.x & 3;
  const int bbx = bh >> 5, h = bh & 31;
  const int i0 = rblk * 16;
  const size_t headbase = ((size_t)bbx * T_ * H_ + h) * 64;

  /* zero-init persistent LDS (full padded areas) */
  for (int p = tid; p < 16 * 68; p += 256) ((float*)Sf)[p] = 0.f;
  for (int p = tid; p < 16 * 72; p += 256) ((u16*)Sbf)[p] = 0;
  for (int p = tid; p < 16 * 40; p += 256) { ((u16*)SAVT)[p] = 0; ((u16*)MK32)[p] = 0; }

  /* per-thread staging slot: 4 consecutive elems (t, j..j+3) */
  const int st_ = tid >> 4;
  const int sj = (tid & 15) * 4;
  const size_t g0 = headbase + (size_t)st_ * C_ + sj;

  uint2 cr, ck, cv, cz, cb; float4 cd;
  cr = *(const uint2*)(rb + g0);
  ck = *(const uint2*)(kb + g0);
  cv = *(const uint2*)(vb + g0);
  cz = *(const uint2*)(zb + g0);
  cb = *(const uint2*)(bbuf + g0);
  cd = *(const float4*)(decb + g0);

  /* prologue: stage chunk-0 dec */
  *(float4*)&Ldec[st_][sj] = cd;
  __syncthreads();

  const int lrow = l & 15, lko = (l >> 4) * 8;

  for (int ch = 0; ch < T_ / 16; ++ch) {
    /* P1: cumulative decay (wave 0, lane = j) */
    if (w == 0) {
      float dv[16];
#pragma unroll
      for (int t = 0; t < 16; ++t) dv[t] = Ldec[t][l];
      float c = 1.f;
      cum[0][l] = 1.f;
#pragma unroll
      for (int t = 0; t < 16; ++t) { c *= dv[t]; cum[t + 1][l] = c; }
    }
    __syncthreads();
    /* P2: scale + write operand matrices; issue next-chunk HBM loads */
    {
      float4 cp = *(const float4*)&cum[st_][sj];
      float4 cc = *(const float4*)&cum[st_ + 1][sj];
      float rv[4], kv[4], zv[4], bv[4];
      rv[0] = bf2f((u16)(cr.x & 0xffff)); rv[1] = bf2f((u16)(cr.x >> 16));
      rv[2] = bf2f((u16)(cr.y & 0xffff)); rv[3] = bf2f((u16)(cr.y >> 16));
      kv[0] = bf2f((u16)(ck.x & 0xffff)); kv[1] = bf2f((u16)(ck.x >> 16));
      kv[2] = bf2f((u16)(ck.y & 0xffff)); kv[3] = bf2f((u16)(ck.y >> 16));
      zv[0] = bf2f((u16)(cz.x & 0xffff)); zv[1] = bf2f((u16)(cz.x >> 16));
      zv[2] = bf2f((u16)(cz.y & 0xffff)); zv[3] = bf2f((u16)(cz.y >> 16));
      bv[0] = bf2f((u16)(cb.x & 0xffff)); bv[1] = bf2f((u16)(cb.x >> 16));
      bv[2] = bf2f((u16)(cb.y & 0xffff)); bv[3] = bf2f((u16)(cb.y >> 16));
      float cpv[4] = {cp.x, cp.y, cp.z, cp.w};
      float ccv[4] = {cc.x, cc.y, cc.z, cc.w};
      u16 zt4[4], rt4[4], bt4[4], kt4[4];
#pragma unroll
      for (int m = 0; m < 4; ++m) {
        float inv = 1.0f / ccv[m];
        zt4[m] = f2bf(zv[m] * cpv[m]);
        rt4[m] = f2bf(rv[m] * ccv[m]);
        bt4[m] = f2bf(bv[m] * inv);
        kt4[m] = f2bf(kv[m] * inv);
      }
      *(uint2*)&Zt[st_][sj] = *(uint2*)zt4;
      *(uint2*)&Rt[st_][sj] = *(uint2*)rt4;
      *(uint2*)&Bt[st_][sj] = *(uint2*)bt4;
      *(uint2*)&Kt[st_][sj] = *(uint2*)kt4;
#pragma unroll
      for (int m = 0; m < 4; ++m) {
        BKT[sj + m][st_] = bt4[m];
        BKT[sj + m][16 + st_] = kt4[m];
      }
      if ((sj >> 4) == rblk) {
        u16 vv4[4];
        vv4[0] = (u16)(cv.x & 0xffff); vv4[1] = (u16)(cv.x >> 16);
        vv4[2] = (u16)(cv.y & 0xffff); vv4[3] = (u16)(cv.y >> 16);
#pragma unroll
        for (int m = 0; m < 4; ++m) SAVT[(sj & 15) + m][16 + st_] = vv4[m];
      }
      if (ch + 1 < T_ / 16) {
        size_t g2 = g0 + (size_t)(ch + 1) * 16 * C_;
        cr = *(const uint2*)(rb + g2);
        ck = *(const uint2*)(kb + g2);
        cv = *(const uint2*)(vb + g2);
        cz = *(const uint2*)(zb + g2);
        cb = *(const uint2*)(bbuf + g2);
        cd = *(const float4*)(decb + g2);
      }
    }
    __syncthreads();
    /* P3: MFMA set A (per-wave) + base/Y part-1.
       w0: M_b = Z~B~^T, keep = Z~S0^T ; w1: M_k = Z~K~^T, keep = R~S0^T ;
       w2: M_rb = R~B~^T ; w3: M_rk = R~K~^T */
    f32x4 keep = {};
    {
      s16x8 a0f, a1f, b0f, b1f;
      if (w == 0 || w == 1) {
        a0f = *(const s16x8*)&Zt[lrow][lko];
        a1f = *(const s16x8*)&Zt[lrow][32 + lko];
      } else {
        a0f = *(const s16x8*)&Rt[lrow][lko];
        a1f = *(const s16x8*)&Rt[lrow][32 + lko];
      }
      if (w == 0 || w == 2) {
        b0f = *(const s16x8*)&Bt[lrow][lko];
        b1f = *(const s16x8*)&Bt[lrow][32 + lko];
      } else {
        b0f = *(const s16x8*)&Kt[lrow][lko];
        b1f = *(const s16x8*)&Kt[lrow][32 + lko];
      }
      f32x4 macc = {};
      macc = __builtin_amdgcn_mfma_f32_16x16x32_bf16(a0f, b0f, macc, 0, 0, 0);
      macc = __builtin_amdgcn_mfma_f32_16x16x32_bf16(a1f, b1f, macc, 0, 0, 0);
      const int s = l & 15;
#pragma unroll
      for (int rr = 0; rr < 4; ++rr) {
        int t = (l >> 4) * 4 + rr;
        float v = macc[rr];
        if (w == 0) Mb[t][s] = (s < t) ? v : 0.f;
        else if (w == 1) MK32[t][16 + s] = f2bf((s < t) ? v : 0.f);
        else if (w == 2) MRBK[t][s] = f2bf((s <= t) ? v : 0.f);
        else MRBK[t][16 + s] = f2bf((s <= t) ? v : 0.f);
      }
      if (w == 0 || w == 1) {
        s16x8 s0f = *(const s16x8*)&Sbf[lrow][lko];
        s16x8 s1f = *(const s16x8*)&Sbf[lrow][32 + lko];
        if (w == 0) {
          keep = __builtin_amdgcn_mfma_f32_16x16x32_bf16(a0f, s0f, keep, 0, 0, 0);
          keep = __builtin_amdgcn_mfma_f32_16x16x32_bf16(a1f, s1f, keep, 0, 0, 0);
        } else {
          s16x8 ra0 = *(const s16x8*)&Rt[lrow][lko];
          s16x8 ra1 = *(const s16x8*)&Rt[lrow][32 + lko];
          keep = __builtin_amdgcn_mfma_f32_16x16x32_bf16(ra0, s0f, keep, 0, 0, 0);
          keep = __builtin_amdgcn_mfma_f32_16x16x32_bf16(ra1, s1f, keep, 0, 0, 0);
        }
      }
    }
    __syncthreads();
    /* P4+P5: wave0: base += [0|M_k] x SAVT ; blocked forward substitution -> SA */
    if (w == 0) {
      s16x8 af = *(const s16x8*)&MK32[lrow][lko];
      s16x8 bf = *(const s16x8*)&SAVT[lrow][lko];
      keep = __builtin_amdgcn_mfma_f32_16x16x32_bf16(af, bf, keep, 0, 0, 0);
      const int i = l & 15;
#pragma unroll
      for (int rr = 0; rr < 4; ++rr) basef[(l >> 4) * 4 + rr][i] = keep[rr];
      float bl[16];
#pragma unroll
      for (int t = 0; t < 16; ++t) bl[t] = basef[t][i];
      float sa[16];
#pragma unroll
      for (int b = 0; b < 4; ++b) {
        const int t0 = 4 * b;
        /* diagonal 4x4 solve: chains <= 3 deep */
        sa[t0] = bl[t0];
        sa[t0 + 1] = bl[t0 + 1] + Mb[t0 + 1][t0] * sa[t0];
        sa[t0 + 2] = bl[t0 + 2] + Mb[t0 + 2][t0] * sa[t0] + Mb[t0 + 2][t0 + 1] * sa[t0 + 1];
        sa[t0 + 3] = bl[t0 + 3] + Mb[t0 + 3][t0] * sa[t0] + Mb[t0 + 3][t0 + 1] * sa[t0 + 1]
                     + Mb[t0 + 3][t0 + 2] * sa[t0 + 2];
        /* rank-4 update of remaining rows (independent, float4 broadcast reads) */
        if (b < 3) {
#pragma unroll
          for (int t = t0 + 4; t < 16; ++t) {
            f32x4 m4 = *(const f32x4*)&Mb[t][t0];
            bl[t] += (m4[0] * sa[t0] + m4[1] * sa[t0 + 1]) + (m4[2] * sa[t0 + 2] + m4[3] * sa[t0 + 3]);
          }
        }
      }
      if (l < 16) {
        u32* dst = (u32*)&SAVT[l][0];
#pragma unroll
        for (int m = 0; m < 8; ++m)
          dst[m] = (u32)f2bf(sa[2 * m]) | ((u32)f2bf(sa[2 * m + 1]) << 16);
      }
    }
    __syncthreads();
    /* P6: Y finish + store (wave1); state update (all waves); stage next dec */
    if (w == 1) {
      s16x8 af = *(const s16x8*)&MRBK[lrow][lko];
      s16x8 bf = *(const s16x8*)&SAVT[lrow][lko];
      f32x4 yacc = __builtin_amdgcn_mfma_f32_16x16x32_bf16(af, bf, keep, 0, 0, 0);
#pragma unroll
      for (int rr = 0; rr < 4; ++rr) {
        int t = (l >> 4) * 4 + rr;
        yb[headbase + (size_t)(ch * 16 + t) * C_ + i0 + (l & 15)] = yacc[rr];
      }
    }
    {
      const int j0 = w * 16;
      s16x8 af = *(const s16x8*)&SAVT[lrow][lko];
      s16x8 bf = *(const s16x8*)&BKT[j0 + lrow][lko];
      f32x4 up = {};
      up = __builtin_amdgcn_mfma_f32_16x16x32_bf16(af, bf, up, 0, 0, 0);
      const int j = j0 + (l & 15);
      float cl = cum[16][j];
#pragma unroll
      for (int rr = 0; rr < 4; ++rr) {
        int i = (l >> 4) * 4 + rr;
        float sn = (Sf[i][j] + up[rr]) * cl;
        Sf[i][j] = sn;
        Sbf[i][j] = f2bf(sn);
      }
    }
    /* stage next chunk's dec (cd prefetched in P2) — replaces P0 */
    *(float4*)&Ldec[st_][sj] = cd;
    __syncthreads();
  }
}

/* ---------------- GroupNorm(64/head) + bonus + gate -> bf16 A for final GEMM ---------------- */
__global__ void __launch_bounds__(256) gn_gg(
    const float* __restrict__ yb, const u16* __restrict__ bonus, const u16* __restrict__ gb,
    const float* __restrict__ gnw, const float* __restrict__ gnb,
    u16* __restrict__ ggb) {
  int rh = blockIdx.x * 4 + (threadIdx.x >> 6);
  int n = threadIdx.x & 63;
  int h = rh & (H_ - 1);
  size_t idx = (size_t)rh * 64 + n;
  int c = h * 64 + n;
  float y = yb[idx];
  float mu = wsum64(y) * (1.f / 64.f);
  float d = y - mu;
  float var = wsum64(d * d) * (1.f / 64.f);
  float yn = d * rsqrtf(var + 6.4e-4f) * gnw[c] + gnb[c];
  ggb[idx] = f2bf((yn + bf2f(bonus[idx])) * bf2f(gb[idx]));
}

extern "C" void kernel_launch(void* const* d_in, const int* in_sizes, int n_in,
                              void* d_out, int out_size, void* d_ws, size_t ws_size,
                              hipStream_t stream) {
  const float* x      = (const float*)d_in[0];
  const float* vfirst = (const float*)d_in[1];
  const float* x_r = (const float*)d_in[2];
  const float* x_w = (const float*)d_in[3];
  const float* x_k = (const float*)d_in[4];
  const float* x_v = (const float*)d_in[5];
  const float* x_a = (const float*)d_in[6];
  const float* x_g = (const float*)d_in[7];
  const float* w0  = (const float*)d_in[8];
  const float* w1  = (const float*)d_in[9];
  const float* w2  = (const float*)d_in[10];
  const float* a0  = (const float*)d_in[11];
  const float* a1  = (const float*)d_in[12];
  const float* a2  = (const float*)d_in[13];
  const float* v0  = (const float*)d_in[14];
  const float* v1  = (const float*)d_in[15];
  const float* v2  = (const float*)d_in[16];
  const float* g1  = (const float*)d_in[17];
  const float* g2  = (const float*)d_in[18];
  const float* k_k = (const float*)d_in[19];
  const float* k_a = (const float*)d_in[20];
  const float* r_k = (const float*)d_in[21];
  const float* W_r = (const float*)d_in[22];
  const float* W_k = (const float*)d_in[23];
  const float* W_v = (const float*)d_in[24];
  const float* W_o = (const float*)d_in[25];
  const float* gnw = (const float*)d_in[26];
  const float* gnb = (const float*)d_in[27];
  float* out = (float*)d_out;

  char* ws = (char*)d_ws;
  size_t off = 0;
  auto alloc = [&](size_t bytes) -> void* {
    void* p = ws + off;
    off += (bytes + 255) & ~(size_t)255;
    return p;
  };
  const size_t MCb2 = MC * 2;

  /* A-region: 6 contiguous 16MiB bf16 mix buffers, later reused */
  u16* xrb = (u16*)alloc(MCb2);   /* A0: xr -> dw_bf -> ggb            */
  u16* xwb = (u16*)alloc(MCb2);   /* A1: xw -> da_bf -> b_bf           */
  u16* xkb = (u16*)alloc(MCb2);   /* A2: xk -> dv_bf -> z_bf           */
  u16* xvb = (u16*)alloc(MCb2);   /* A3: xv -> g_bf                    */
  u16* xab = (u16*)alloc(MCb2);   /* A4: xa ┐                          */
  u16* xgb = (u16*)alloc(MCb2);   /* A5: xg ┘ -> yb fp32 (32MiB)       */
  u16* Wrb = (u16*)alloc((size_t)C_ * C_ * 2);
  u16* Wkb = (u16*)alloc((size_t)C_ * C_ * 2);
  u16* Wvb = (u16*)alloc((size_t)C_ * C_ * 2);
  u16* Wob = (u16*)alloc((size_t)C_ * C_ * 2);
  u16* w1t = (u16*)alloc((size_t)64 * C_ * 2);
  u16* a1t = (u16*)alloc((size_t)64 * C_ * 2);
  u16* v1t = (u16*)alloc((size_t)32 * C_ * 2);
  u16* g1t = (u16*)alloc((size_t)128 * C_ * 2);
  u16* w2t = (u16*)alloc((size_t)C_ * 64 * 2);
  u16* a2t = (u16*)alloc((size_t)C_ * 64 * 2);
  u16* v2t = (u16*)alloc((size_t)C_ * 32 * 2);
  u16* g2t = (u16*)alloc((size_t)C_ * 128 * 2);
  float* hw = (float*)alloc((size_t)M_ * 64 * 4 * 2);   /* 2 split-K partials */
  float* ha = (float*)alloc((size_t)M_ * 64 * 4 * 2);
  float* hv = (float*)alloc((size_t)M_ * 32 * 4 * 2);
  float* hg = (float*)alloc((size_t)M_ * 128 * 4 * 2);
  u16* hwb = (u16*)alloc((size_t)M_ * 64 * 2);
  u16* hab = (u16*)alloc((size_t)M_ * 64 * 2);
  u16* hvb = (u16*)alloc((size_t)M_ * 32 * 2);
  u16* hgb = (u16*)alloc((size_t)M_ * 128 * 2);
  u16* r_bf = (u16*)alloc(MCb2);            /* D0 */
  u16* k_bf = (u16*)alloc(MCb2);            /* D1: k -> k2 in place */
  u16* v_bf = (u16*)alloc(MCb2);            /* D2: v -> v2 in place */
  float* dec = (float*)alloc(MC * 4);       /* E0 fp32 */
  u16* bonus  = (u16*)alloc(MCb2);          /* E1 */
  /* aliases (regions dead at write time; see schedule) */
  u16* dw_bf = xrb;
  u16* da_bf = xwb;
  u16* dv_bf = xkb;
  u16* g_bf  = xvb;
  float* yb  = (float*)xab;  /* spans xab+xgb = 32 MiB */
  u16* ggb   = xrb;          /* after dw_bf consumed   */
  (void)ws_size; (void)in_sizes; (void)n_in; (void)out_size;

  dim3 blk(256);

  /* weight conversion: 2 fused launches */
  convbf8x4<<<dim3(C_ * C_ / 8 / 256, 4), blk, 0, stream>>>(W_r, W_k, W_v, W_o, Wrb, Wkb, Wvb, Wob);
  tconvbf8<<<dim3(1024, 8), blk, 0, stream>>>(w1, a1, v1, g1, w2, a2, v2, g2,
                                              w1t, a1t, v1t, g1t, w2t, a2t, v2t, g2t);

  /* time-shift mixes, v_first passthrough */
  prep_mix<<<(int)(MC / 8 / 256), blk, 0, stream>>>(x, x_r, x_w, x_k, x_v, x_a, x_g,
                                                    xrb, xwb, xkb, xvb, xab, xgb);
  hipMemcpyAsync(out + MC, vfirst, MC * sizeof(float), hipMemcpyDeviceToDevice, stream);

  /* big GEMMs r,k,v: one fused launch */
  {
    GTab4 t;
    t.A[0] = xrb; t.Bm[0] = Wrb; t.Cm[0] = r_bf; t.K[0] = 2048;
    t.A[1] = xkb; t.Bm[1] = Wkb; t.Cm[1] = k_bf; t.K[1] = 2048;
    t.A[2] = xvb; t.Bm[2] = Wvb; t.Cm[2] = v_bf; t.K[2] = 2048;
    t.A[3] = xrb; t.Bm[3] = Wrb; t.Cm[3] = r_bf; t.K[3] = 2048;
    gemm128z<<<dim3(M_ / 128, C_ / 128, 3), blk, 0, stream>>>(t, M_, C_);
  }

  /* LoRA stage-1: fused, split-K 2 -> fp32 partials */
  gemm_lora1<<<dim3(M_ / 128, 9, 2), blk, 0, stream>>>(xwb, xab, xvb, xgb,
                                                       w1t, a1t, v1t, g1t,
                                                       hw, ha, hv, hg);

  /* fused activation + partial-sum + bf16 */
  act_lora<<<dim3(M_ * 288 / 256), blk, 0, stream>>>(hw, ha, hv, hg, hwb, hab, hvb, hgb);

  /* LoRA stage-2: one fused launch (bf16 out, into dead mix regions) */
  {
    GTab4 t;
    t.A[0] = hwb; t.Bm[0] = w2t; t.Cm[0] = dw_bf; t.K[0] = 64;
    t.A[1] = hab; t.Bm[1] = a2t; t.Cm[1] = da_bf; t.K[1] = 64;
    t.A[2] = hvb; t.Bm[2] = v2t; t.Cm[2] = dv_bf; t.K[2] = 32;
    t.A[3] = hgb; t.Bm[3] = g2t; t.Cm[3] = g_bf;  t.K[3] = 128;
    gemm128z<<<dim3(M_ / 128, C_ / 128, 4), blk, 0, stream>>>(t, M_, C_);
  }

  /* scan inputs (in-place bf16) + dec fp32 + bonus bf16 */
  scan_prep<<<M_ * H_ / 4, blk, 0, stream>>>(r_bf, k_bf, v_bf, dw_bf, da_bf, dv_bf, vfirst,
                                             a0, v0, w0, k_k, k_a, r_k, dec, bonus);

  /* chunked scan: 256 blocks (64 heads x 4 row-slices) x 256 threads */
  rwkv_scan<<<dim3(256), dim3(256), 0, stream>>>(r_bf, dec, k_bf, v_bf, dv_bf, da_bf, yb);

  /* GroupNorm + bonus + gate -> bf16 */
  gn_gg<<<M_ * H_ / 4, blk, 0, stream>>>(yb, bonus, g_bf, gnw, gnb, ggb);

  /* output projection (fp32 out) */
  gemm128f<<<dim3(M_ / 128, C_ / 128), blk, 0, stream>>>(ggb, Wob, out, M_, C_, C_);
}